// Round 12
// baseline (2910.894 us; speedup 1.0000x reference)
//
#include <hip/hip_runtime.h>
#include <math.h>

// Problem constants (fixed by reference)
#define T_STEPS 24
#define N_NODES 20000
#define F_IN 64
#define H_DIM 256
#define H3 (3 * H_DIM)
#define TC 4                    // timestep chunk for the encoder
#define NCHUNK (T_STEPS / TC)   // 6
#define GRU_BM_GRPS 160         // padded row-groups (157 real) ; 160 % 8 == 0

using f16x8 = __attribute__((ext_vector_type(8))) _Float16;
using f16x4 = __attribute__((ext_vector_type(4))) _Float16;
using f16x2 = __attribute__((ext_vector_type(2))) _Float16;
using f32x4 = __attribute__((ext_vector_type(4))) float;

__device__ __forceinline__ void gload_lds16(const void* g, void* l) {
    __builtin_amdgcn_global_load_lds(
        (const __attribute__((address_space(1))) void*)(uintptr_t)g,
        (__attribute__((address_space(3))) void*)l, 16, 0, 0);
}

__device__ __forceinline__ float sigmoidf_(float x) { return 1.0f / (1.0f + expf(-x)); }

// ---------------------------------------------------------------------------
// Norm / CSR build kernels
// ---------------------------------------------------------------------------
__global__ void init_deg_kernel(float* deg, int* indeg, int n) {
    int i = blockIdx.x * blockDim.x + threadIdx.x;
    if (i < n) { deg[i] = 1.0f; indeg[i] = 0; }
}

__global__ void accum_deg_kernel(const int* __restrict__ src, const int* __restrict__ dst,
                                 const float* __restrict__ ew, float* deg, int* indeg, int E) {
    int e = blockIdx.x * blockDim.x + threadIdx.x;
    if (e < E) {
        atomicAdd(&deg[dst[e]], ew[e]);
        atomicAdd(&indeg[dst[e]], 1);
    }
}

__global__ void dinv_kernel(float* deg, float* selfnorm, int n) {
    int i = blockIdx.x * blockDim.x + threadIdx.x;
    if (i < n) {
        float d = deg[i];
        float di = (d > 0.0f) ? rsqrtf(d) : 0.0f;
        deg[i] = di;
        selfnorm[i] = di * di;
    }
}

__global__ void edge_norm_kernel(const int* __restrict__ src, const int* __restrict__ dst,
                                 const float* __restrict__ ew, const float* __restrict__ dinv,
                                 float* norm, int E) {
    int e = blockIdx.x * blockDim.x + threadIdx.x;
    if (e < E) norm[e] = dinv[src[e]] * ew[e] * dinv[dst[e]];
}

__global__ void scan_kernel(const int* __restrict__ indeg, int* offs, int* cursor, int N) {
    __shared__ int part[1024];
    int t = threadIdx.x;
    const int CH = (N + 1023) / 1024;
    int s = 0;
    for (int i = 0; i < CH; i++) {
        int idx = t * CH + i;
        if (idx < N) s += indeg[idx];
    }
    part[t] = s;
    __syncthreads();
    for (int off = 1; off < 1024; off <<= 1) {
        int v = (t >= off) ? part[t - off] : 0;
        __syncthreads();
        part[t] += v;
        __syncthreads();
    }
    int base = (t == 0) ? 0 : part[t - 1];
    for (int i = 0; i < CH; i++) {
        int idx = t * CH + i;
        if (idx < N) {
            offs[idx] = base;
            cursor[idx] = base;
            base += indeg[idx];
        }
    }
    if (t == 0) offs[N] = part[1023];
}

__global__ void csr_fill_kernel(const int* __restrict__ src, const int* __restrict__ dst,
                                const float* __restrict__ norm, int* cursor,
                                int* csr_src, float* csr_norm, int E) {
    int e = blockIdx.x * blockDim.x + threadIdx.x;
    if (e < E) {
        int d = dst[e];
        int pos = atomicAdd(&cursor[d], 1);
        csr_src[pos] = src[e];
        csr_norm[pos] = norm[e];
    }
}

// ---------------------------------------------------------------------------
// Weight pack (fp16): P[kk][c][j], j=0..7, kk=k/8.
// trans=0: B = W [K,N] row-major.
// trans=2: B = W^T with gate-block-interleaved columns:
//          c -> a=c/48, w=c%48, g=w/16, b=w&15, orig row = g*256 + a*16 + b.
// ---------------------------------------------------------------------------
__global__ void pack_b16_kernel(const float* __restrict__ W, _Float16* __restrict__ P,
                                int K, int Nn, int trans) {
    int idx = blockIdx.x * blockDim.x + threadIdx.x;
    int total = (K >> 3) * Nn;
    if (idx >= total) return;
    int kk = idx / Nn, c = idx - kk * Nn;
    int n = c;
    if (trans == 2) {
        int a = c / 48, w = c % 48;
        int g = w >> 4, b = w & 15;
        n = g * 256 + a * 16 + b;
    }
    size_t o = (size_t)idx * 8;
    for (int j = 0; j < 8; ++j) {
        float v = (trans != 0) ? W[(size_t)n * K + kk * 8 + j] : W[(size_t)(kk * 8 + j) * Nn + n];
        P[o + j] = (_Float16)v;
    }
}

// Permute a [768] bias into gate-block-interleaved order.
__global__ void perm_bias_kernel(const float* __restrict__ b, float* __restrict__ pb) {
    int c = blockIdx.x * blockDim.x + threadIdx.x;
    if (c < H3) {
        int a = c / 48, w = c % 48;
        int g = w >> 4, bb = w & 15;
        pb[c] = b[g * 256 + a * 16 + bb];
    }
}

// fp32 -> fp16 (vectorized x4)
__global__ void tofp16_kernel(const float* __restrict__ in, _Float16* __restrict__ out, int n4) {
    int i = blockIdx.x * blockDim.x + threadIdx.x;
    if (i < n4) {
        float4 v = ((const float4*)in)[i];
        f16x4 o = { (_Float16)v.x, (_Float16)v.y, (_Float16)v.z, (_Float16)v.w };
        ((f16x4*)out)[i] = o;
    }
}

// ---------------------------------------------------------------------------
// agg1 (chunked over TC): fp16 gather. One wave per node, 8-way edge-parallel
// lanes (8 lanes x f16x8 = 128B row), 2-deep unroll (16 edges in flight).
// ---------------------------------------------------------------------------
__global__ void agg1_kernel(const _Float16* __restrict__ xs, const int* __restrict__ offs,
                            const int* __restrict__ csr_src, const float* __restrict__ csr_norm,
                            const float* __restrict__ selfnorm,
                            _Float16* __restrict__ out, int N) {
    int t = blockIdx.y;
    int n = blockIdx.x * 4 + (threadIdx.x >> 6);
    int lane = threadIdx.x & 63;
    int fg = lane & 7, ep = lane >> 3;     // 8 feature-lanes x 8 edge-groups
    const _Float16* xsl = xs + (size_t)t * N * F_IN;
    float acc[8] = {};
    int e0 = offs[n], e1 = offs[n + 1];
    int e = e0 + ep;
    for (; e + 8 < e1; e += 16) {
        int sA = csr_src[e], sB = csr_src[e + 8];
        float wA = csr_norm[e], wB = csr_norm[e + 8];
        f16x8 vA = *(const f16x8*)&xsl[(size_t)sA * F_IN + fg * 8];
        f16x8 vB = *(const f16x8*)&xsl[(size_t)sB * F_IN + fg * 8];
#pragma unroll
        for (int c = 0; c < 8; ++c) acc[c] = fmaf(wA, (float)vA[c], acc[c]);
#pragma unroll
        for (int c = 0; c < 8; ++c) acc[c] = fmaf(wB, (float)vB[c], acc[c]);
    }
    if (e < e1) {
        int s = csr_src[e];
        float w = csr_norm[e];
        f16x8 v = *(const f16x8*)&xsl[(size_t)s * F_IN + fg * 8];
#pragma unroll
        for (int c = 0; c < 8; ++c) acc[c] = fmaf(w, (float)v[c], acc[c]);
    }
#pragma unroll
    for (int c = 0; c < 8; ++c) {
        acc[c] += __shfl_xor(acc[c], 8, 64);
        acc[c] += __shfl_xor(acc[c], 16, 64);
        acc[c] += __shfl_xor(acc[c], 32, 64);
    }
    f16x8 own = *(const f16x8*)&xsl[(size_t)n * F_IN + fg * 8];
    float sn = selfnorm[n];
#pragma unroll
    for (int c = 0; c < 8; ++c) acc[c] = fmaf(sn, (float)own[c], acc[c]);
    if (ep == 0) {
        f16x8 o;
#pragma unroll
        for (int c = 0; c < 8; ++c) o[c] = (_Float16)acc[c];
        *(f16x8*)&out[((size_t)t * N + n) * F_IN + fg * 8] = o;
    }
}

// ---------------------------------------------------------------------------
// agg2: XCD-sliced gather. 256 features split into 8 col-slices of 32;
// 1-D grid with cs = id % 8 -> all blocks of slice cs land on XCD cs
// (round-robin dispatch), so the per-XCD working set (h1 slice 1.28 MB +
// csr 2.56 MB) is L2-resident. One wave per (node, cs): 8 edge-groups x
// 8 feature-lanes (f16x4 = 64B/row-slice), 2-deep unroll.
// grid: (N/4) * 8 * TC blocks of 256.
// ---------------------------------------------------------------------------
__global__ void agg2_kernel(const _Float16* __restrict__ hs, const int* __restrict__ offs,
                            const int* __restrict__ csr_src, const float* __restrict__ csr_norm,
                            const float* __restrict__ selfnorm,
                            _Float16* __restrict__ out, int N) {
    int id = blockIdx.x;
    int cs = id & 7;                 // col-slice -> XCD
    int rest = id >> 3;
    int ngrp = rest % (N_NODES / 4);
    int t = rest / (N_NODES / 4);
    int n = ngrp * 4 + (threadIdx.x >> 6);
    int lane = threadIdx.x & 63;
    int fg = lane & 7, ep = lane >> 3;           // 8 feature-lanes x 8 edge-groups
    int col = cs * 32 + fg * 4;                  // 4 consecutive features
    const _Float16* hsl = hs + (size_t)t * N * H_DIM;
    f32x4 acc = (f32x4){0.f, 0.f, 0.f, 0.f};
    int e0 = offs[n], e1 = offs[n + 1];
    int e = e0 + ep;
    for (; e + 8 < e1; e += 16) {
        int sA = csr_src[e], sB = csr_src[e + 8];
        float wA = csr_norm[e], wB = csr_norm[e + 8];
        f16x4 vA = *(const f16x4*)&hsl[(size_t)sA * H_DIM + col];
        f16x4 vB = *(const f16x4*)&hsl[(size_t)sB * H_DIM + col];
#pragma unroll
        for (int c = 0; c < 4; ++c) acc[c] = fmaf(wA, (float)vA[c], acc[c]);
#pragma unroll
        for (int c = 0; c < 4; ++c) acc[c] = fmaf(wB, (float)vB[c], acc[c]);
    }
    if (e < e1) {
        int s = csr_src[e];
        float w = csr_norm[e];
        f16x4 v = *(const f16x4*)&hsl[(size_t)s * H_DIM + col];
#pragma unroll
        for (int c = 0; c < 4; ++c) acc[c] = fmaf(w, (float)v[c], acc[c]);
    }
#pragma unroll
    for (int c = 0; c < 4; ++c) {
        acc[c] += __shfl_xor(acc[c], 8, 64);
        acc[c] += __shfl_xor(acc[c], 16, 64);
        acc[c] += __shfl_xor(acc[c], 32, 64);
    }
    f16x4 own = *(const f16x4*)&hsl[(size_t)n * H_DIM + col];
    float sn = selfnorm[n];
#pragma unroll
    for (int c = 0; c < 4; ++c) acc[c] = fmaf(sn, (float)own[c], acc[c]);
    if (ep == 0) {
        f16x4 o = { (_Float16)acc[0], (_Float16)acc[1], (_Float16)acc[2], (_Float16)acc[3] };
        *(f16x4*)&out[((size_t)t * N + n) * H_DIM + col] = o;
    }
}

// ---------------------------------------------------------------------------
// conv1: fp16 MFMA GEMM, 128x128 tile, BK=32, bias + leaky -> fp16.
// SWAPPED operands: mfma(b, a, acc) => lane(kq,r) reg q holds
// C[row = wm+i*16+r][col = wn+j*16+kq*4+q] -> f16x4 stores.
// ---------------------------------------------------------------------------
__global__ __launch_bounds__(256, 4)
void conv1_kernel(const _Float16* __restrict__ A, const _Float16* __restrict__ Bp,
                  const float* __restrict__ bias, _Float16* __restrict__ C16,
                  int M, int Nn, int K) {
    __shared__ _Float16 As[4][128][8];
    __shared__ _Float16 Bs[4][128][8];

    const int tid = threadIdx.x;
    const int wave = tid >> 6, lane = tid & 63;
    const int bm = blockIdx.x * 128, bn = blockIdx.y * 128;
    const int wm = (wave >> 1) * 64, wn = (wave & 1) * 64;
    const int kq = lane >> 4, r = lane & 15;

    f32x4 acc[4][4];
#pragma unroll
    for (int i = 0; i < 4; ++i)
#pragma unroll
        for (int j = 0; j < 4; ++j) acc[i][j] = (f32x4){0.f, 0.f, 0.f, 0.f};

    for (int k0 = 0; k0 < K; k0 += 32) {
        __syncthreads();
        const int kb = k0 >> 3;
#pragma unroll
        for (int it = 0; it < 2; ++it) {
            int c = it * 256 + tid;
            int kk = c >> 7, idx = c & 127;
            int row = bm + idx;
            if (row >= M) row = M - 1;
            size_t aoff = (size_t)row * K + k0 + kk * 8;
            size_t boff = ((size_t)(kb + kk) * Nn + bn + idx) * 8;
            gload_lds16(A + aoff, &As[0][0][0] + (size_t)c * 8);
            gload_lds16(Bp + boff, &Bs[0][0][0] + (size_t)c * 8);
        }
        __syncthreads();

        f16x8 a[4], b[4];
#pragma unroll
        for (int f = 0; f < 4; ++f) {
            a[f] = *(const f16x8*)&As[kq][wm + f * 16 + r][0];
            b[f] = *(const f16x8*)&Bs[kq][wn + f * 16 + r][0];
        }
#pragma unroll
        for (int i = 0; i < 4; ++i)
#pragma unroll
            for (int j = 0; j < 4; ++j)
                acc[i][j] = __builtin_amdgcn_mfma_f32_16x16x32_f16(b[j], a[i], acc[i][j], 0, 0, 0);
    }

#pragma unroll
    for (int j = 0; j < 4; ++j) {
        int colb = bn + wn + j * 16 + kq * 4;
        float4 bv = *(const float4*)&bias[colb];
#pragma unroll
        for (int i = 0; i < 4; ++i) {
            int row = bm + wm + i * 16 + r;   // grid covers M exactly (M % 128 == 0)
            f16x4 o;
#pragma unroll
            for (int q = 0; q < 4; ++q) {
                float v = acc[i][j][q] + ((const float*)&bv)[q];
                v = (v >= 0.0f) ? v : 0.01f * v;
                o[q] = (_Float16)v;
            }
            *(f16x4*)&C16[(size_t)row * Nn + colb] = o;
        }
    }
}

// ---------------------------------------------------------------------------
// conv2 + LayerNorm fused (SWAPPED operands): C = A @ W2 + b2; LN per row.
// BM=128, BN=256, 4 waves 2x2 (wave 64x128, acc 4x8). Lane(kq,r) reg q holds
// C[row = wm+i*16+r][col = wn+j*16+kq*4+q]; row-sum = lane 32-sum + kq shfls.
// ---------------------------------------------------------------------------
__global__ __launch_bounds__(256, 2)
void conv2ln_kernel(const _Float16* __restrict__ A, const _Float16* __restrict__ Bp,
                    const float* __restrict__ b2, const float* __restrict__ lnw,
                    const float* __restrict__ lnb, _Float16* __restrict__ out, int M) {
    __shared__ _Float16 As[4][128][8];   // 8 KB
    __shared__ _Float16 Bs[4][256][8];   // 16 KB
    __shared__ float lnP[128][2][2];     // 2 KB

    const int tid = threadIdx.x;
    const int wave = tid >> 6, lane = tid & 63;
    const int bm = blockIdx.x * 128;
    const int wm = (wave >> 1) * 64, wn = (wave & 1) * 128;
    const int cw = wave & 1;
    const int kq = lane >> 4, r = lane & 15;

    f32x4 acc[4][8];
#pragma unroll
    for (int i = 0; i < 4; ++i)
#pragma unroll
        for (int j = 0; j < 8; ++j) acc[i][j] = (f32x4){0.f, 0.f, 0.f, 0.f};

    for (int k0 = 0; k0 < H_DIM; k0 += 32) {
        __syncthreads();
        const int kb = k0 >> 3;
#pragma unroll
        for (int it = 0; it < 2; ++it) {
            int c = it * 256 + tid;
            int kk = c >> 7, idx = c & 127;
            int row = bm + idx;
            if (row >= M) row = M - 1;
            gload_lds16(A + (size_t)row * H_DIM + k0 + kk * 8, &As[0][0][0] + (size_t)c * 8);
        }
#pragma unroll
        for (int it = 0; it < 4; ++it) {
            int c = it * 256 + tid;
            int kk = c >> 8, col = c & 255;
            gload_lds16(Bp + ((size_t)(kb + kk) * H_DIM + col) * 8, &Bs[0][0][0] + (size_t)c * 8);
        }
        __syncthreads();

        f16x8 a[4], b[8];
#pragma unroll
        for (int f = 0; f < 4; ++f) a[f] = *(const f16x8*)&As[kq][wm + f * 16 + r][0];
#pragma unroll
        for (int f = 0; f < 8; ++f) b[f] = *(const f16x8*)&Bs[kq][wn + f * 16 + r][0];
#pragma unroll
        for (int i = 0; i < 4; ++i)
#pragma unroll
            for (int j = 0; j < 8; ++j)
                acc[i][j] = __builtin_amdgcn_mfma_f32_16x16x32_f16(b[j], a[i], acc[i][j], 0, 0, 0);
    }

    // bias add + per-row partial sums: lane's 32 values all belong to row wm+i*16+r
#pragma unroll
    for (int i = 0; i < 4; ++i) {
        float s = 0.f, s2 = 0.f;
#pragma unroll
        for (int j = 0; j < 8; ++j) {
            float4 bv = *(const float4*)&b2[wn + j * 16 + kq * 4];
#pragma unroll
            for (int q = 0; q < 4; ++q) {
                float v = acc[i][j][q] + ((const float*)&bv)[q];
                acc[i][j][q] = v;
                s += v;
                s2 += v * v;
            }
        }
        // combine the 4 kq lanes sharing this row
        s += __shfl_xor(s, 16, 64);  s2 += __shfl_xor(s2, 16, 64);
        s += __shfl_xor(s, 32, 64);  s2 += __shfl_xor(s2, 32, 64);
        int lrow = wm + i * 16 + r;
        if (kq == 0) { lnP[lrow][cw][0] = s; lnP[lrow][cw][1] = s2; }
    }
    __syncthreads();

#pragma unroll
    for (int i = 0; i < 4; ++i) {
        int lrow = wm + i * 16 + r;
        int row = bm + lrow;   // grid covers M exactly
        float S = lnP[lrow][0][0] + lnP[lrow][1][0];
        float S2 = lnP[lrow][0][1] + lnP[lrow][1][1];
        float mu = S * (1.0f / H_DIM);
        float var = S2 * (1.0f / H_DIM) - mu * mu;
        float rstd = rsqrtf(var + 1e-5f);
#pragma unroll
        for (int j = 0; j < 8; ++j) {
            int colb = wn + j * 16 + kq * 4;
            float4 wv = *(const float4*)&lnw[colb];
            float4 bvv = *(const float4*)&lnb[colb];
            f16x4 o;
#pragma unroll
            for (int q = 0; q < 4; ++q)
                o[q] = (_Float16)((acc[i][j][q] - mu) * rstd * ((const float*)&wv)[q] + ((const float*)&bvv)[q]);
            *(f16x4*)&out[(size_t)row * H_DIM + colb] = o;
        }
    }
}

// ---------------------------------------------------------------------------
// Fused GRU step (SWAPPED operands): gh = h@Whh^T, gi = e@Wih^T
// (gate-block-interleaved cols), r/z accs shared. BM=128, BN=96, 4 waves 2x2.
// Lane(kq,r) reg q holds gate value for feature agrp*16 + kq*4 + q of
// row wm+i*16+r -> f16x4 h-load/store. XCD-swizzled 1-D grid.
// ---------------------------------------------------------------------------
__global__ __launch_bounds__(256, 3)
void gru_step_kernel(const _Float16* __restrict__ hprev, const _Float16* __restrict__ e,
                     const _Float16* __restrict__ Bhh, const _Float16* __restrict__ Bih,
                     const float* __restrict__ pbhh, const float* __restrict__ pbih,
                     _Float16* __restrict__ hnew, int M) {
    const int bid = blockIdx.x;
    const int bn_grp = bid / GRU_BM_GRPS;        // 0..7
    const int bm_grp = bid - bn_grp * GRU_BM_GRPS;
    if (bm_grp * 128 >= M) return;               // padding block
    const int bm = bm_grp * 128, bn = bn_grp * 96;

    __shared__ _Float16 Ah[4][128][8];   // 8 KB
    __shared__ _Float16 Ae[4][128][8];   // 8 KB
    __shared__ _Float16 Bsh[4][96][8];   // 6 KB
    __shared__ _Float16 Bsi[4][96][8];   // 6 KB

    const int tid = threadIdx.x;
    const int wave = tid >> 6, lane = tid & 63;
    const int wm = (wave >> 1) * 64, wn = (wave & 1) * 48;
    const int kq = lane >> 4, r = lane & 15;

    f32x4 arz[4][2], ahn[4], ainn[4];
#pragma unroll
    for (int i = 0; i < 4; ++i) {
        arz[i][0] = (f32x4){0.f, 0.f, 0.f, 0.f};
        arz[i][1] = (f32x4){0.f, 0.f, 0.f, 0.f};
        ahn[i] = (f32x4){0.f, 0.f, 0.f, 0.f};
        ainn[i] = (f32x4){0.f, 0.f, 0.f, 0.f};
    }

    for (int k0 = 0; k0 < H_DIM; k0 += 32) {
        __syncthreads();
        const int kb = k0 >> 3;
#pragma unroll
        for (int it = 0; it < 2; ++it) {
            int c = it * 256 + tid;
            int kk = c >> 7, idx = c & 127;
            int row = bm + idx;
            if (row >= M) row = M - 1;
            size_t ao = (size_t)row * H_DIM + k0 + kk * 8;
            gload_lds16(hprev + ao, &Ah[0][0][0] + (size_t)c * 8);
            gload_lds16(e + ao, &Ae[0][0][0] + (size_t)c * 8);
        }
        {
            int c = tid;
            int kk = c / 96, col = c - kk * 96;
            size_t bo = ((size_t)(kb + kk) * H3 + bn + col) * 8;
            gload_lds16(Bhh + bo, &Bsh[0][0][0] + (size_t)c * 8);
            gload_lds16(Bih + bo, &Bsi[0][0][0] + (size_t)c * 8);
            if (tid < 128) {
                int c2 = 256 + tid;
                int kk2 = c2 / 96, col2 = c2 - kk2 * 96;
                size_t bo2 = ((size_t)(kb + kk2) * H3 + bn + col2) * 8;
                gload_lds16(Bhh + bo2, &Bsh[0][0][0] + (size_t)c2 * 8);
                gload_lds16(Bih + bo2, &Bsi[0][0][0] + (size_t)c2 * 8);
            }
        }
        __syncthreads();

        f16x8 ah[4], ae[4], bh[3], bi[3];
#pragma unroll
        for (int f = 0; f < 4; ++f) {
            ah[f] = *(const f16x8*)&Ah[kq][wm + f * 16 + r][0];
            ae[f] = *(const f16x8*)&Ae[kq][wm + f * 16 + r][0];
        }
#pragma unroll
        for (int f = 0; f < 3; ++f) {
            bh[f] = *(const f16x8*)&Bsh[kq][wn + f * 16 + r][0];
            bi[f] = *(const f16x8*)&Bsi[kq][wn + f * 16 + r][0];
        }
#pragma unroll
        for (int i = 0; i < 4; ++i) {
            arz[i][0] = __builtin_amdgcn_mfma_f32_16x16x32_f16(bh[0], ah[i], arz[i][0], 0, 0, 0);
            arz[i][0] = __builtin_amdgcn_mfma_f32_16x16x32_f16(bi[0], ae[i], arz[i][0], 0, 0, 0);
            arz[i][1] = __builtin_amdgcn_mfma_f32_16x16x32_f16(bh[1], ah[i], arz[i][1], 0, 0, 0);
            arz[i][1] = __builtin_amdgcn_mfma_f32_16x16x32_f16(bi[1], ae[i], arz[i][1], 0, 0, 0);
            ahn[i] = __builtin_amdgcn_mfma_f32_16x16x32_f16(bh[2], ah[i], ahn[i], 0, 0, 0);
            ainn[i] = __builtin_amdgcn_mfma_f32_16x16x32_f16(bi[2], ae[i], ainn[i], 0, 0, 0);
        }
    }

    // Epilogue: lane holds gates for features fb..fb+3 of rows wm+i*16+r.
    const int colbase = bn + wn;           // multiple of 48
    const int agrp = colbase / 48;         // 0..15
    const int fb = agrp * 16 + kq * 4;     // feature base (4 consecutive)
    float b_r[4], b_z[4], b_hn[4], b_in[4];
#pragma unroll
    for (int q = 0; q < 4; ++q) {
        int cq = colbase + kq * 4 + q;
        b_r[q]  = pbhh[cq] + pbih[cq];
        b_z[q]  = pbhh[cq + 16] + pbih[cq + 16];
        b_hn[q] = pbhh[cq + 32];
        b_in[q] = pbih[cq + 32];
    }
#pragma unroll
    for (int i = 0; i < 4; ++i) {
        int row = bm + wm + i * 16 + r;
        if (row < M) {
            f16x4 hp = *(const f16x4*)&hprev[(size_t)row * H_DIM + fb];
            f16x4 o;
#pragma unroll
            for (int q = 0; q < 4; ++q) {
                float rg = sigmoidf_(arz[i][0][q] + b_r[q]);
                float zg = sigmoidf_(arz[i][1][q] + b_z[q]);
                float nn = tanhf(ainn[i][q] + b_in[q] + rg * (ahn[i][q] + b_hn[q]));
                o[q] = (_Float16)((1.0f - zg) * nn + zg * (float)hp[q]);
            }
            *(f16x4*)&hnew[(size_t)row * H_DIM + fb] = o;
        }
    }
}

// ---------------------------------------------------------------------------
// fc: out[n] = dot(h16[n,:], Wfc[0,:]) + bfc
// ---------------------------------------------------------------------------
__global__ void fc_kernel(const _Float16* __restrict__ h, const float* __restrict__ Wfc,
                          const float* __restrict__ bfc, float* __restrict__ out, int N) {
    int n = blockIdx.x * 4 + (threadIdx.x >> 6);
    int lane = threadIdx.x & 63;
    if (n >= N) return;
    f16x4 hv = *(const f16x4*)&h[(size_t)n * H_DIM + lane * 4];
    float4 wv = *(const float4*)&Wfc[lane * 4];
    float acc = (float)hv[0] * wv.x + (float)hv[1] * wv.y + (float)hv[2] * wv.z + (float)hv[3] * wv.w;
#pragma unroll
    for (int o = 32; o > 0; o >>= 1) acc += __shfl_down(acc, o, 64);
    if (lane == 0) out[n] = acc + bfc[0];
}

// ---------------------------------------------------------------------------
// Launch
// ---------------------------------------------------------------------------
extern "C" void kernel_launch(void* const* d_in, const int* in_sizes, int n_in,
                              void* d_out, int out_size, void* d_ws, size_t ws_size,
                              hipStream_t stream) {
    const float* x   = (const float*)d_in[0];
    const int* eidx  = (const int*)d_in[1];
    const float* ew  = (const float*)d_in[2];
    const float* W1  = (const float*)d_in[3];
    const float* b1  = (const float*)d_in[4];
    const float* W2  = (const float*)d_in[5];
    const float* b2  = (const float*)d_in[6];
    const float* lnw = (const float*)d_in[7];
    const float* lnb = (const float*)d_in[8];
    const float* Wih = (const float*)d_in[9];
    const float* Whh = (const float*)d_in[10];
    const float* bih = (const float*)d_in[11];
    const float* bhh = (const float*)d_in[12];
    const float* Wfc = (const float*)d_in[13];
    const float* bfc = (const float*)d_in[14];

    const int E = in_sizes[2];
    const int N = N_NODES;
    const int* src = eidx;
    const int* dst = eidx + E;

    uintptr_t p = (uintptr_t)d_ws;
    auto alloc = [&](size_t bytes) -> void* {
        p = (p + 255) & ~(uintptr_t)255;
        void* r = (void*)p;
        p += bytes;
        return r;
    };
    // CSR / norm
    float* deg      = (float*)alloc(N * sizeof(float));
    float* selfnorm = (float*)alloc(N * sizeof(float));
    float* norm     = (float*)alloc(E * sizeof(float));
    int* indeg      = (int*)alloc(N * sizeof(int));
    int* offs       = (int*)alloc((N + 1) * sizeof(int));
    int* cursor     = (int*)alloc(N * sizeof(int));
    int* csr_src    = (int*)alloc(E * sizeof(int));
    float* csr_norm = (float*)alloc(E * sizeof(float));
    // packed fp16 weights + permuted biases
    _Float16* W1p   = (_Float16*)alloc((size_t)F_IN * H_DIM * sizeof(_Float16));
    _Float16* W2p   = (_Float16*)alloc((size_t)H_DIM * H_DIM * sizeof(_Float16));
    _Float16* Wihp  = (_Float16*)alloc((size_t)H_DIM * H3 * sizeof(_Float16));
    _Float16* Whhp  = (_Float16*)alloc((size_t)H_DIM * H3 * sizeof(_Float16));
    float* pbih     = (float*)alloc(H3 * sizeof(float));
    float* pbhh     = (float*)alloc(H3 * sizeof(float));
    // chunk activations (TC timesteps)
    _Float16* xs16  = (_Float16*)alloc((size_t)TC * N * F_IN * sizeof(_Float16));
    _Float16* a1_16 = (_Float16*)alloc((size_t)TC * N * F_IN * sizeof(_Float16));
    _Float16* h1_16 = (_Float16*)alloc((size_t)TC * N * H_DIM * sizeof(_Float16));
    _Float16* a2_16 = (_Float16*)alloc((size_t)TC * N * H_DIM * sizeof(_Float16));
    _Float16* e16   = (_Float16*)alloc((size_t)TC * N * H_DIM * sizeof(_Float16));
    // recurrent state (double-buffered)
    _Float16* h_a   = (_Float16*)alloc((size_t)N * H_DIM * sizeof(_Float16));
    _Float16* h_b   = (_Float16*)alloc((size_t)N * H_DIM * sizeof(_Float16));

    const int TB = 256;
    hipLaunchKernelGGL(init_deg_kernel, dim3((N + TB - 1) / TB), dim3(TB), 0, stream, deg, indeg, N);
    hipLaunchKernelGGL(accum_deg_kernel, dim3((E + TB - 1) / TB), dim3(TB), 0, stream, src, dst, ew, deg, indeg, E);
    hipLaunchKernelGGL(dinv_kernel, dim3((N + TB - 1) / TB), dim3(TB), 0, stream, deg, selfnorm, N);
    hipLaunchKernelGGL(edge_norm_kernel, dim3((E + TB - 1) / TB), dim3(TB), 0, stream, src, dst, ew, deg, norm, E);
    hipLaunchKernelGGL(scan_kernel, dim3(1), dim3(1024), 0, stream, indeg, offs, cursor, N);
    hipLaunchKernelGGL(csr_fill_kernel, dim3((E + TB - 1) / TB), dim3(TB), 0, stream, src, dst, norm, cursor, csr_src, csr_norm, E);

    // weight packs (fp16) + permuted biases
    {
        int tot = (F_IN / 8) * H_DIM;
        hipLaunchKernelGGL(pack_b16_kernel, dim3((tot + TB - 1) / TB), dim3(TB), 0, stream, W1, W1p, F_IN, H_DIM, 0);
        tot = (H_DIM / 8) * H_DIM;
        hipLaunchKernelGGL(pack_b16_kernel, dim3((tot + TB - 1) / TB), dim3(TB), 0, stream, W2, W2p, H_DIM, H_DIM, 0);
        tot = (H_DIM / 8) * H3;
        hipLaunchKernelGGL(pack_b16_kernel, dim3((tot + TB - 1) / TB), dim3(TB), 0, stream, Wih, Wihp, H_DIM, H3, 2);
        hipLaunchKernelGGL(pack_b16_kernel, dim3((tot + TB - 1) / TB), dim3(TB), 0, stream, Whh, Whhp, H_DIM, H3, 2);
        hipLaunchKernelGGL(perm_bias_kernel, dim3((H3 + TB - 1) / TB), dim3(TB), 0, stream, bih, pbih);
        hipLaunchKernelGGL(perm_bias_kernel, dim3((H3 + TB - 1) / TB), dim3(TB), 0, stream, bhh, pbhh);
    }

    hipMemsetAsync(h_a, 0, (size_t)N * H_DIM * sizeof(_Float16), stream);

    const int MC = TC * N;                   // 80000 (= 625 * 128 exactly)
    dim3 gb(256);
    dim3 g_conv1(MC / 128, H_DIM / 128);     // (625, 2)
    dim3 g_c2ln(MC / 128);                   // (625)
    dim3 g_gru(8 * GRU_BM_GRPS);             // 1280, XCD-swizzled
    dim3 g_agg1(N / 4, TC);                  // (5000, 4)
    dim3 g_agg2((N / 4) * 8 * TC);           // 160000, 1-D: cs = id%8 -> XCD-pinned slice

    _Float16* h_cur = h_a;
    _Float16* h_nxt = h_b;

    for (int chunk = 0; chunk < NCHUNK; ++chunk) {
        const float* xc = x + (size_t)chunk * TC * N * F_IN;
        // x -> fp16 (whole chunk)
        int n4 = TC * N * F_IN / 4;
        hipLaunchKernelGGL(tofp16_kernel, dim3((n4 + TB - 1) / TB), dim3(TB), 0, stream, xc, xs16, n4);
        // agg1: a1 = A @ x  (fp16 gather, exact commute)
        hipLaunchKernelGGL(agg1_kernel, g_agg1, dim3(256), 0, stream,
                           xs16, offs, csr_src, csr_norm, selfnorm, a1_16, N);
        // conv1: h1 = leaky(a1 @ W1 + b1) -> fp16
        hipLaunchKernelGGL(conv1_kernel, g_conv1, gb, 0, stream,
                           a1_16, W1p, b1, h1_16, MC, H_DIM, F_IN);
        // agg2: a2 = A @ h1  (XCD-sliced, L2-resident gather)
        hipLaunchKernelGGL(agg2_kernel, g_agg2, dim3(256), 0, stream,
                           h1_16, offs, csr_src, csr_norm, selfnorm, a2_16, N);
        // conv2 + LN fused -> e16
        hipLaunchKernelGGL(conv2ln_kernel, g_c2ln, gb, 0, stream,
                           a2_16, W2p, b2, lnw, lnb, e16, MC);
        // sequential GRU: fused gi+gh GEMMs + pointwise, double-buffered h
        for (int tc = 0; tc < TC; ++tc) {
            hipLaunchKernelGGL(gru_step_kernel, g_gru, gb, 0, stream,
                               h_cur, e16 + (size_t)tc * N * H_DIM, Whhp, Wihp,
                               pbhh, pbih, h_nxt, N);
            _Float16* tmp = h_cur; h_cur = h_nxt; h_nxt = tmp;
        }
    }

    hipLaunchKernelGGL(fc_kernel, dim3((N + 3) / 4), dim3(256), 0, stream, h_cur, Wfc, bfc, (float*)d_out, N);
}

// Round 13
// 2120.549 us; speedup vs baseline: 1.3727x; 1.3727x over previous
//
#include <hip/hip_runtime.h>
#include <math.h>

// Problem constants (fixed by reference)
#define T_STEPS 24
#define N_NODES 20000
#define F_IN 64
#define H_DIM 256
#define H3 (3 * H_DIM)
#define TC 8                    // timestep chunk for the encoder
#define NCHUNK (T_STEPS / TC)   // 3
#define GRU_BM_GRPS 160         // padded row-groups (157 real) ; 160 % 8 == 0

using f16x8 = __attribute__((ext_vector_type(8))) _Float16;
using f16x4 = __attribute__((ext_vector_type(4))) _Float16;
using f16x2 = __attribute__((ext_vector_type(2))) _Float16;
using f32x4 = __attribute__((ext_vector_type(4))) float;

__device__ __forceinline__ void gload_lds16(const void* g, void* l) {
    __builtin_amdgcn_global_load_lds(
        (const __attribute__((address_space(1))) void*)(uintptr_t)g,
        (__attribute__((address_space(3))) void*)l, 16, 0, 0);
}

__device__ __forceinline__ float sigmoidf_(float x) { return 1.0f / (1.0f + expf(-x)); }

// ---------------------------------------------------------------------------
// Norm / CSR build kernels
// ---------------------------------------------------------------------------
__global__ void init_deg_kernel(float* deg, int* indeg, int n) {
    int i = blockIdx.x * blockDim.x + threadIdx.x;
    if (i < n) { deg[i] = 1.0f; indeg[i] = 0; }
}

__global__ void accum_deg_kernel(const int* __restrict__ src, const int* __restrict__ dst,
                                 const float* __restrict__ ew, float* deg, int* indeg, int E) {
    int e = blockIdx.x * blockDim.x + threadIdx.x;
    if (e < E) {
        atomicAdd(&deg[dst[e]], ew[e]);
        atomicAdd(&indeg[dst[e]], 1);
    }
}

__global__ void dinv_kernel(float* deg, float* selfnorm, int n) {
    int i = blockIdx.x * blockDim.x + threadIdx.x;
    if (i < n) {
        float d = deg[i];
        float di = (d > 0.0f) ? rsqrtf(d) : 0.0f;
        deg[i] = di;
        selfnorm[i] = di * di;
    }
}

__global__ void edge_norm_kernel(const int* __restrict__ src, const int* __restrict__ dst,
                                 const float* __restrict__ ew, const float* __restrict__ dinv,
                                 float* norm, int E) {
    int e = blockIdx.x * blockDim.x + threadIdx.x;
    if (e < E) norm[e] = dinv[src[e]] * ew[e] * dinv[dst[e]];
}

__global__ void scan_kernel(const int* __restrict__ indeg, int* offs, int* cursor, int N) {
    __shared__ int part[1024];
    int t = threadIdx.x;
    const int CH = (N + 1023) / 1024;
    int s = 0;
    for (int i = 0; i < CH; i++) {
        int idx = t * CH + i;
        if (idx < N) s += indeg[idx];
    }
    part[t] = s;
    __syncthreads();
    for (int off = 1; off < 1024; off <<= 1) {
        int v = (t >= off) ? part[t - off] : 0;
        __syncthreads();
        part[t] += v;
        __syncthreads();
    }
    int base = (t == 0) ? 0 : part[t - 1];
    for (int i = 0; i < CH; i++) {
        int idx = t * CH + i;
        if (idx < N) {
            offs[idx] = base;
            cursor[idx] = base;
            base += indeg[idx];
        }
    }
    if (t == 0) offs[N] = part[1023];
}

__global__ void csr_fill_kernel(const int* __restrict__ src, const int* __restrict__ dst,
                                const float* __restrict__ norm, int* cursor,
                                int* csr_src, float* csr_norm, int E) {
    int e = blockIdx.x * blockDim.x + threadIdx.x;
    if (e < E) {
        int d = dst[e];
        int pos = atomicAdd(&cursor[d], 1);
        csr_src[pos] = src[e];
        csr_norm[pos] = norm[e];
    }
}

// ---------------------------------------------------------------------------
// Weight pack (fp16): P[kk][c][j], j=0..7, kk=k/8.
// trans=0: B = W [K,N] row-major.
// trans=2: B = W^T with gate-block-interleaved columns:
//          c -> a=c/48, w=c%48, g=w/16, b=w&15, orig row = g*256 + a*16 + b.
// ---------------------------------------------------------------------------
__global__ void pack_b16_kernel(const float* __restrict__ W, _Float16* __restrict__ P,
                                int K, int Nn, int trans) {
    int idx = blockIdx.x * blockDim.x + threadIdx.x;
    int total = (K >> 3) * Nn;
    if (idx >= total) return;
    int kk = idx / Nn, c = idx - kk * Nn;
    int n = c;
    if (trans == 2) {
        int a = c / 48, w = c % 48;
        int g = w >> 4, b = w & 15;
        n = g * 256 + a * 16 + b;
    }
    size_t o = (size_t)idx * 8;
    for (int j = 0; j < 8; ++j) {
        float v = (trans != 0) ? W[(size_t)n * K + kk * 8 + j] : W[(size_t)(kk * 8 + j) * Nn + n];
        P[o + j] = (_Float16)v;
    }
}

// Permute a [768] bias into gate-block-interleaved order.
__global__ void perm_bias_kernel(const float* __restrict__ b, float* __restrict__ pb) {
    int c = blockIdx.x * blockDim.x + threadIdx.x;
    if (c < H3) {
        int a = c / 48, w = c % 48;
        int g = w >> 4, bb = w & 15;
        pb[c] = b[g * 256 + a * 16 + bb];
    }
}

// fp32 -> fp16 (vectorized x4)
__global__ void tofp16_kernel(const float* __restrict__ in, _Float16* __restrict__ out, int n4) {
    int i = blockIdx.x * blockDim.x + threadIdx.x;
    if (i < n4) {
        float4 v = ((const float4*)in)[i];
        f16x4 o = { (_Float16)v.x, (_Float16)v.y, (_Float16)v.z, (_Float16)v.w };
        ((f16x4*)out)[i] = o;
    }
}

// ---------------------------------------------------------------------------
// agg1 (chunked over TC): fp16 gather. One wave per node, 8-way edge-parallel
// lanes (8 lanes x f16x8 = 128B row), 2-deep unroll (16 edges in flight).
// ---------------------------------------------------------------------------
__global__ void agg1_kernel(const _Float16* __restrict__ xs, const int* __restrict__ offs,
                            const int* __restrict__ csr_src, const float* __restrict__ csr_norm,
                            const float* __restrict__ selfnorm,
                            _Float16* __restrict__ out, int N) {
    int t = blockIdx.y;
    int n = blockIdx.x * 4 + (threadIdx.x >> 6);
    int lane = threadIdx.x & 63;
    int fg = lane & 7, ep = lane >> 3;     // 8 feature-lanes x 8 edge-groups
    const _Float16* xsl = xs + (size_t)t * N * F_IN;
    float acc[8] = {};
    int e0 = offs[n], e1 = offs[n + 1];
    int e = e0 + ep;
    for (; e + 8 < e1; e += 16) {
        int sA = csr_src[e], sB = csr_src[e + 8];
        float wA = csr_norm[e], wB = csr_norm[e + 8];
        f16x8 vA = *(const f16x8*)&xsl[(size_t)sA * F_IN + fg * 8];
        f16x8 vB = *(const f16x8*)&xsl[(size_t)sB * F_IN + fg * 8];
#pragma unroll
        for (int c = 0; c < 8; ++c) acc[c] = fmaf(wA, (float)vA[c], acc[c]);
#pragma unroll
        for (int c = 0; c < 8; ++c) acc[c] = fmaf(wB, (float)vB[c], acc[c]);
    }
    if (e < e1) {
        int s = csr_src[e];
        float w = csr_norm[e];
        f16x8 v = *(const f16x8*)&xsl[(size_t)s * F_IN + fg * 8];
#pragma unroll
        for (int c = 0; c < 8; ++c) acc[c] = fmaf(w, (float)v[c], acc[c]);
    }
#pragma unroll
    for (int c = 0; c < 8; ++c) {
        acc[c] += __shfl_xor(acc[c], 8, 64);
        acc[c] += __shfl_xor(acc[c], 16, 64);
        acc[c] += __shfl_xor(acc[c], 32, 64);
    }
    f16x8 own = *(const f16x8*)&xsl[(size_t)n * F_IN + fg * 8];
    float sn = selfnorm[n];
#pragma unroll
    for (int c = 0; c < 8; ++c) acc[c] = fmaf(sn, (float)own[c], acc[c]);
    if (ep == 0) {
        f16x8 o;
#pragma unroll
        for (int c = 0; c < 8; ++c) o[c] = (_Float16)acc[c];
        *(f16x8*)&out[((size_t)t * N + n) * F_IN + fg * 8] = o;
    }
}

// ---------------------------------------------------------------------------
// agg2 (chunked over TC): one wave per node, HALF-WAVE per edge
// (32 lanes x f16x8 = 512B row). 4 edges per half per iter (8 rows in
// flight/wave). Cross-half combine via one shfl_xor(32).   [round-11 version]
// ---------------------------------------------------------------------------
__global__ void agg2_kernel(const _Float16* __restrict__ hs, const int* __restrict__ offs,
                            const int* __restrict__ csr_src, const float* __restrict__ csr_norm,
                            const float* __restrict__ selfnorm,
                            _Float16* __restrict__ out, int N) {
    int t = blockIdx.y;
    int n = blockIdx.x * 4 + (threadIdx.x >> 6);
    int lane = threadIdx.x & 63;
    int half = lane >> 5, fl = lane & 31;   // 32 feature-lanes x 2 edge-halves
    const _Float16* hsl = hs + (size_t)t * N * H_DIM;
    float acc[8] = {};
    int e0 = offs[n], e1 = offs[n + 1];
    int e = e0;
    // main: 8 edges/iter, half h takes contiguous run [e+4h, e+4h+4)
    for (; e + 8 <= e1; e += 8) {
        int eb = e + half * 4;
        int s0 = csr_src[eb], s1 = csr_src[eb + 1], s2 = csr_src[eb + 2], s3 = csr_src[eb + 3];
        float w0 = csr_norm[eb], w1 = csr_norm[eb + 1], w2 = csr_norm[eb + 2], w3 = csr_norm[eb + 3];
        f16x8 v0 = *(const f16x8*)&hsl[(size_t)s0 * H_DIM + fl * 8];
        f16x8 v1 = *(const f16x8*)&hsl[(size_t)s1 * H_DIM + fl * 8];
        f16x8 v2 = *(const f16x8*)&hsl[(size_t)s2 * H_DIM + fl * 8];
        f16x8 v3 = *(const f16x8*)&hsl[(size_t)s3 * H_DIM + fl * 8];
#pragma unroll
        for (int c = 0; c < 8; ++c) acc[c] = fmaf(w0, (float)v0[c], acc[c]);
#pragma unroll
        for (int c = 0; c < 8; ++c) acc[c] = fmaf(w1, (float)v1[c], acc[c]);
#pragma unroll
        for (int c = 0; c < 8; ++c) acc[c] = fmaf(w2, (float)v2[c], acc[c]);
#pragma unroll
        for (int c = 0; c < 8; ++c) acc[c] = fmaf(w3, (float)v3[c], acc[c]);
    }
    // pairs: one edge per half
    for (; e + 2 <= e1; e += 2) {
        int eb = e + half;
        int s = csr_src[eb];
        float w = csr_norm[eb];
        f16x8 v = *(const f16x8*)&hsl[(size_t)s * H_DIM + fl * 8];
#pragma unroll
        for (int c = 0; c < 8; ++c) acc[c] = fmaf(w, (float)v[c], acc[c]);
    }
    // last odd edge (half 0 only)
    if (e < e1 && half == 0) {
        int s = csr_src[e];
        float w = csr_norm[e];
        f16x8 v = *(const f16x8*)&hsl[(size_t)s * H_DIM + fl * 8];
#pragma unroll
        for (int c = 0; c < 8; ++c) acc[c] = fmaf(w, (float)v[c], acc[c]);
    }
#pragma unroll
    for (int c = 0; c < 8; ++c) acc[c] += __shfl_xor(acc[c], 32, 64);
    f16x8 own = *(const f16x8*)&hsl[(size_t)n * H_DIM + fl * 8];
    float sn = selfnorm[n];
#pragma unroll
    for (int c = 0; c < 8; ++c) acc[c] = fmaf(sn, (float)own[c], acc[c]);
    if (half == 0) {
        f16x8 o;
#pragma unroll
        for (int c = 0; c < 8; ++c) o[c] = (_Float16)acc[c];
        *(f16x8*)&out[((size_t)t * N + n) * H_DIM + fl * 8] = o;
    }
}

// ---------------------------------------------------------------------------
// conv1: fp16 MFMA GEMM, 128x128 tile, BK=32, bias + leaky -> fp16.
// SWAPPED operands: mfma(b, a, acc) => lane(kq,r) reg q holds
// C[row = wm+i*16+r][col = wn+j*16+kq*4+q] -> f16x4 stores.
// ---------------------------------------------------------------------------
__global__ __launch_bounds__(256, 4)
void conv1_kernel(const _Float16* __restrict__ A, const _Float16* __restrict__ Bp,
                  const float* __restrict__ bias, _Float16* __restrict__ C16,
                  int M, int Nn, int K) {
    __shared__ _Float16 As[4][128][8];
    __shared__ _Float16 Bs[4][128][8];

    const int tid = threadIdx.x;
    const int wave = tid >> 6, lane = tid & 63;
    const int bm = blockIdx.x * 128, bn = blockIdx.y * 128;
    const int wm = (wave >> 1) * 64, wn = (wave & 1) * 64;
    const int kq = lane >> 4, r = lane & 15;

    f32x4 acc[4][4];
#pragma unroll
    for (int i = 0; i < 4; ++i)
#pragma unroll
        for (int j = 0; j < 4; ++j) acc[i][j] = (f32x4){0.f, 0.f, 0.f, 0.f};

    for (int k0 = 0; k0 < K; k0 += 32) {
        __syncthreads();
        const int kb = k0 >> 3;
#pragma unroll
        for (int it = 0; it < 2; ++it) {
            int c = it * 256 + tid;
            int kk = c >> 7, idx = c & 127;
            int row = bm + idx;
            if (row >= M) row = M - 1;
            size_t aoff = (size_t)row * K + k0 + kk * 8;
            size_t boff = ((size_t)(kb + kk) * Nn + bn + idx) * 8;
            gload_lds16(A + aoff, &As[0][0][0] + (size_t)c * 8);
            gload_lds16(Bp + boff, &Bs[0][0][0] + (size_t)c * 8);
        }
        __syncthreads();

        f16x8 a[4], b[4];
#pragma unroll
        for (int f = 0; f < 4; ++f) {
            a[f] = *(const f16x8*)&As[kq][wm + f * 16 + r][0];
            b[f] = *(const f16x8*)&Bs[kq][wn + f * 16 + r][0];
        }
#pragma unroll
        for (int i = 0; i < 4; ++i)
#pragma unroll
            for (int j = 0; j < 4; ++j)
                acc[i][j] = __builtin_amdgcn_mfma_f32_16x16x32_f16(b[j], a[i], acc[i][j], 0, 0, 0);
    }

#pragma unroll
    for (int j = 0; j < 4; ++j) {
        int colb = bn + wn + j * 16 + kq * 4;
        float4 bv = *(const float4*)&bias[colb];
#pragma unroll
        for (int i = 0; i < 4; ++i) {
            int row = bm + wm + i * 16 + r;   // grid covers M exactly (M % 128 == 0)
            f16x4 o;
#pragma unroll
            for (int q = 0; q < 4; ++q) {
                float v = acc[i][j][q] + ((const float*)&bv)[q];
                v = (v >= 0.0f) ? v : 0.01f * v;
                o[q] = (_Float16)v;
            }
            *(f16x4*)&C16[(size_t)row * Nn + colb] = o;
        }
    }
}

// ---------------------------------------------------------------------------
// conv2 + LayerNorm fused (SWAPPED operands): C = A @ W2 + b2; LN per row.
// BM=128, BN=256, 4 waves 2x2 (wave 64x128, acc 4x8). Lane(kq,r) reg q holds
// C[row = wm+i*16+r][col = wn+j*16+kq*4+q]; row-sum = lane 32-sum + kq shfls.
// ---------------------------------------------------------------------------
__global__ __launch_bounds__(256, 2)
void conv2ln_kernel(const _Float16* __restrict__ A, const _Float16* __restrict__ Bp,
                    const float* __restrict__ b2, const float* __restrict__ lnw,
                    const float* __restrict__ lnb, _Float16* __restrict__ out, int M) {
    __shared__ _Float16 As[4][128][8];   // 8 KB
    __shared__ _Float16 Bs[4][256][8];   // 16 KB
    __shared__ float lnP[128][2][2];     // 2 KB

    const int tid = threadIdx.x;
    const int wave = tid >> 6, lane = tid & 63;
    const int bm = blockIdx.x * 128;
    const int wm = (wave >> 1) * 64, wn = (wave & 1) * 128;
    const int cw = wave & 1;
    const int kq = lane >> 4, r = lane & 15;

    f32x4 acc[4][8];
#pragma unroll
    for (int i = 0; i < 4; ++i)
#pragma unroll
        for (int j = 0; j < 8; ++j) acc[i][j] = (f32x4){0.f, 0.f, 0.f, 0.f};

    for (int k0 = 0; k0 < H_DIM; k0 += 32) {
        __syncthreads();
        const int kb = k0 >> 3;
#pragma unroll
        for (int it = 0; it < 2; ++it) {
            int c = it * 256 + tid;
            int kk = c >> 7, idx = c & 127;
            int row = bm + idx;
            if (row >= M) row = M - 1;
            gload_lds16(A + (size_t)row * H_DIM + k0 + kk * 8, &As[0][0][0] + (size_t)c * 8);
        }
#pragma unroll
        for (int it = 0; it < 4; ++it) {
            int c = it * 256 + tid;
            int kk = c >> 8, col = c & 255;
            gload_lds16(Bp + ((size_t)(kb + kk) * H_DIM + col) * 8, &Bs[0][0][0] + (size_t)c * 8);
        }
        __syncthreads();

        f16x8 a[4], b[8];
#pragma unroll
        for (int f = 0; f < 4; ++f) a[f] = *(const f16x8*)&As[kq][wm + f * 16 + r][0];
#pragma unroll
        for (int f = 0; f < 8; ++f) b[f] = *(const f16x8*)&Bs[kq][wn + f * 16 + r][0];
#pragma unroll
        for (int i = 0; i < 4; ++i)
#pragma unroll
            for (int j = 0; j < 8; ++j)
                acc[i][j] = __builtin_amdgcn_mfma_f32_16x16x32_f16(b[j], a[i], acc[i][j], 0, 0, 0);
    }

    // bias add + per-row partial sums: lane's 32 values all belong to row wm+i*16+r
#pragma unroll
    for (int i = 0; i < 4; ++i) {
        float s = 0.f, s2 = 0.f;
#pragma unroll
        for (int j = 0; j < 8; ++j) {
            float4 bv = *(const float4*)&b2[wn + j * 16 + kq * 4];
#pragma unroll
            for (int q = 0; q < 4; ++q) {
                float v = acc[i][j][q] + ((const float*)&bv)[q];
                acc[i][j][q] = v;
                s += v;
                s2 += v * v;
            }
        }
        // combine the 4 kq lanes sharing this row
        s += __shfl_xor(s, 16, 64);  s2 += __shfl_xor(s2, 16, 64);
        s += __shfl_xor(s, 32, 64);  s2 += __shfl_xor(s2, 32, 64);
        int lrow = wm + i * 16 + r;
        if (kq == 0) { lnP[lrow][cw][0] = s; lnP[lrow][cw][1] = s2; }
    }
    __syncthreads();

#pragma unroll
    for (int i = 0; i < 4; ++i) {
        int lrow = wm + i * 16 + r;
        int row = bm + lrow;   // grid covers M exactly
        float S = lnP[lrow][0][0] + lnP[lrow][1][0];
        float S2 = lnP[lrow][0][1] + lnP[lrow][1][1];
        float mu = S * (1.0f / H_DIM);
        float var = S2 * (1.0f / H_DIM) - mu * mu;
        float rstd = rsqrtf(var + 1e-5f);
#pragma unroll
        for (int j = 0; j < 8; ++j) {
            int colb = wn + j * 16 + kq * 4;
            float4 wv = *(const float4*)&lnw[colb];
            float4 bvv = *(const float4*)&lnb[colb];
            f16x4 o;
#pragma unroll
            for (int q = 0; q < 4; ++q)
                o[q] = (_Float16)((acc[i][j][q] - mu) * rstd * ((const float*)&wv)[q] + ((const float*)&bvv)[q]);
            *(f16x4*)&out[(size_t)row * H_DIM + colb] = o;
        }
    }
}

// ---------------------------------------------------------------------------
// Fused GRU step (SWAPPED operands): gh = h@Whh^T, gi = e@Wih^T
// (gate-block-interleaved cols), r/z accs shared. BM=128, BN=96, 4 waves 2x2.
// Lane(kq,r) reg q holds gate value for feature agrp*16 + kq*4 + q of
// row wm+i*16+r -> f16x4 h-load/store. XCD-swizzled 1-D grid.
// ---------------------------------------------------------------------------
__global__ __launch_bounds__(256, 3)
void gru_step_kernel(const _Float16* __restrict__ hprev, const _Float16* __restrict__ e,
                     const _Float16* __restrict__ Bhh, const _Float16* __restrict__ Bih,
                     const float* __restrict__ pbhh, const float* __restrict__ pbih,
                     _Float16* __restrict__ hnew, int M) {
    const int bid = blockIdx.x;
    const int bn_grp = bid / GRU_BM_GRPS;        // 0..7
    const int bm_grp = bid - bn_grp * GRU_BM_GRPS;
    if (bm_grp * 128 >= M) return;               // padding block
    const int bm = bm_grp * 128, bn = bn_grp * 96;

    __shared__ _Float16 Ah[4][128][8];   // 8 KB
    __shared__ _Float16 Ae[4][128][8];   // 8 KB
    __shared__ _Float16 Bsh[4][96][8];   // 6 KB
    __shared__ _Float16 Bsi[4][96][8];   // 6 KB

    const int tid = threadIdx.x;
    const int wave = tid >> 6, lane = tid & 63;
    const int wm = (wave >> 1) * 64, wn = (wave & 1) * 48;
    const int kq = lane >> 4, r = lane & 15;

    f32x4 arz[4][2], ahn[4], ainn[4];
#pragma unroll
    for (int i = 0; i < 4; ++i) {
        arz[i][0] = (f32x4){0.f, 0.f, 0.f, 0.f};
        arz[i][1] = (f32x4){0.f, 0.f, 0.f, 0.f};
        ahn[i] = (f32x4){0.f, 0.f, 0.f, 0.f};
        ainn[i] = (f32x4){0.f, 0.f, 0.f, 0.f};
    }

    for (int k0 = 0; k0 < H_DIM; k0 += 32) {
        __syncthreads();
        const int kb = k0 >> 3;
#pragma unroll
        for (int it = 0; it < 2; ++it) {
            int c = it * 256 + tid;
            int kk = c >> 7, idx = c & 127;
            int row = bm + idx;
            if (row >= M) row = M - 1;
            size_t ao = (size_t)row * H_DIM + k0 + kk * 8;
            gload_lds16(hprev + ao, &Ah[0][0][0] + (size_t)c * 8);
            gload_lds16(e + ao, &Ae[0][0][0] + (size_t)c * 8);
        }
        {
            int c = tid;
            int kk = c / 96, col = c - kk * 96;
            size_t bo = ((size_t)(kb + kk) * H3 + bn + col) * 8;
            gload_lds16(Bhh + bo, &Bsh[0][0][0] + (size_t)c * 8);
            gload_lds16(Bih + bo, &Bsi[0][0][0] + (size_t)c * 8);
            if (tid < 128) {
                int c2 = 256 + tid;
                int kk2 = c2 / 96, col2 = c2 - kk2 * 96;
                size_t bo2 = ((size_t)(kb + kk2) * H3 + bn + col2) * 8;
                gload_lds16(Bhh + bo2, &Bsh[0][0][0] + (size_t)c2 * 8);
                gload_lds16(Bih + bo2, &Bsi[0][0][0] + (size_t)c2 * 8);
            }
        }
        __syncthreads();

        f16x8 ah[4], ae[4], bh[3], bi[3];
#pragma unroll
        for (int f = 0; f < 4; ++f) {
            ah[f] = *(const f16x8*)&Ah[kq][wm + f * 16 + r][0];
            ae[f] = *(const f16x8*)&Ae[kq][wm + f * 16 + r][0];
        }
#pragma unroll
        for (int f = 0; f < 3; ++f) {
            bh[f] = *(const f16x8*)&Bsh[kq][wn + f * 16 + r][0];
            bi[f] = *(const f16x8*)&Bsi[kq][wn + f * 16 + r][0];
        }
#pragma unroll
        for (int i = 0; i < 4; ++i) {
            arz[i][0] = __builtin_amdgcn_mfma_f32_16x16x32_f16(bh[0], ah[i], arz[i][0], 0, 0, 0);
            arz[i][0] = __builtin_amdgcn_mfma_f32_16x16x32_f16(bi[0], ae[i], arz[i][0], 0, 0, 0);
            arz[i][1] = __builtin_amdgcn_mfma_f32_16x16x32_f16(bh[1], ah[i], arz[i][1], 0, 0, 0);
            arz[i][1] = __builtin_amdgcn_mfma_f32_16x16x32_f16(bi[1], ae[i], arz[i][1], 0, 0, 0);
            ahn[i] = __builtin_amdgcn_mfma_f32_16x16x32_f16(bh[2], ah[i], ahn[i], 0, 0, 0);
            ainn[i] = __builtin_amdgcn_mfma_f32_16x16x32_f16(bi[2], ae[i], ainn[i], 0, 0, 0);
        }
    }

    // Epilogue: lane holds gates for features fb..fb+3 of rows wm+i*16+r.
    const int colbase = bn + wn;           // multiple of 48
    const int agrp = colbase / 48;         // 0..15
    const int fb = agrp * 16 + kq * 4;     // feature base (4 consecutive)
    float b_r[4], b_z[4], b_hn[4], b_in[4];
#pragma unroll
    for (int q = 0; q < 4; ++q) {
        int cq = colbase + kq * 4 + q;
        b_r[q]  = pbhh[cq] + pbih[cq];
        b_z[q]  = pbhh[cq + 16] + pbih[cq + 16];
        b_hn[q] = pbhh[cq + 32];
        b_in[q] = pbih[cq + 32];
    }
#pragma unroll
    for (int i = 0; i < 4; ++i) {
        int row = bm + wm + i * 16 + r;
        if (row < M) {
            f16x4 hp = *(const f16x4*)&hprev[(size_t)row * H_DIM + fb];
            f16x4 o;
#pragma unroll
            for (int q = 0; q < 4; ++q) {
                float rg = sigmoidf_(arz[i][0][q] + b_r[q]);
                float zg = sigmoidf_(arz[i][1][q] + b_z[q]);
                float nn = tanhf(ainn[i][q] + b_in[q] + rg * (ahn[i][q] + b_hn[q]));
                o[q] = (_Float16)((1.0f - zg) * nn + zg * (float)hp[q]);
            }
            *(f16x4*)&hnew[(size_t)row * H_DIM + fb] = o;
        }
    }
}

// ---------------------------------------------------------------------------
// fc: out[n] = dot(h16[n,:], Wfc[0,:]) + bfc
// ---------------------------------------------------------------------------
__global__ void fc_kernel(const _Float16* __restrict__ h, const float* __restrict__ Wfc,
                          const float* __restrict__ bfc, float* __restrict__ out, int N) {
    int n = blockIdx.x * 4 + (threadIdx.x >> 6);
    int lane = threadIdx.x & 63;
    if (n >= N) return;
    f16x4 hv = *(const f16x4*)&h[(size_t)n * H_DIM + lane * 4];
    float4 wv = *(const float4*)&Wfc[lane * 4];
    float acc = (float)hv[0] * wv.x + (float)hv[1] * wv.y + (float)hv[2] * wv.z + (float)hv[3] * wv.w;
#pragma unroll
    for (int o = 32; o > 0; o >>= 1) acc += __shfl_down(acc, o, 64);
    if (lane == 0) out[n] = acc + bfc[0];
}

// ---------------------------------------------------------------------------
// Launch
// ---------------------------------------------------------------------------
extern "C" void kernel_launch(void* const* d_in, const int* in_sizes, int n_in,
                              void* d_out, int out_size, void* d_ws, size_t ws_size,
                              hipStream_t stream) {
    const float* x   = (const float*)d_in[0];
    const int* eidx  = (const int*)d_in[1];
    const float* ew  = (const float*)d_in[2];
    const float* W1  = (const float*)d_in[3];
    const float* b1  = (const float*)d_in[4];
    const float* W2  = (const float*)d_in[5];
    const float* b2  = (const float*)d_in[6];
    const float* lnw = (const float*)d_in[7];
    const float* lnb = (const float*)d_in[8];
    const float* Wih = (const float*)d_in[9];
    const float* Whh = (const float*)d_in[10];
    const float* bih = (const float*)d_in[11];
    const float* bhh = (const float*)d_in[12];
    const float* Wfc = (const float*)d_in[13];
    const float* bfc = (const float*)d_in[14];

    const int E = in_sizes[2];
    const int N = N_NODES;
    const int* src = eidx;
    const int* dst = eidx + E;

    uintptr_t p = (uintptr_t)d_ws;
    auto alloc = [&](size_t bytes) -> void* {
        p = (p + 255) & ~(uintptr_t)255;
        void* r = (void*)p;
        p += bytes;
        return r;
    };
    // CSR / norm
    float* deg      = (float*)alloc(N * sizeof(float));
    float* selfnorm = (float*)alloc(N * sizeof(float));
    float* norm     = (float*)alloc(E * sizeof(float));
    int* indeg      = (int*)alloc(N * sizeof(int));
    int* offs       = (int*)alloc((N + 1) * sizeof(int));
    int* cursor     = (int*)alloc(N * sizeof(int));
    int* csr_src    = (int*)alloc(E * sizeof(int));
    float* csr_norm = (float*)alloc(E * sizeof(float));
    // packed fp16 weights + permuted biases
    _Float16* W1p   = (_Float16*)alloc((size_t)F_IN * H_DIM * sizeof(_Float16));
    _Float16* W2p   = (_Float16*)alloc((size_t)H_DIM * H_DIM * sizeof(_Float16));
    _Float16* Wihp  = (_Float16*)alloc((size_t)H_DIM * H3 * sizeof(_Float16));
    _Float16* Whhp  = (_Float16*)alloc((size_t)H_DIM * H3 * sizeof(_Float16));
    float* pbih     = (float*)alloc(H3 * sizeof(float));
    float* pbhh     = (float*)alloc(H3 * sizeof(float));
    // chunk activations (TC=8 timesteps)
    _Float16* xs16  = (_Float16*)alloc((size_t)TC * N * F_IN * sizeof(_Float16));   // 20.5 MB
    _Float16* a1_16 = (_Float16*)alloc((size_t)TC * N * F_IN * sizeof(_Float16));   // 20.5 MB
    _Float16* h1_16 = (_Float16*)alloc((size_t)TC * N * H_DIM * sizeof(_Float16));  // 82 MB
    _Float16* a2_16 = (_Float16*)alloc((size_t)TC * N * H_DIM * sizeof(_Float16));  // 82 MB
    _Float16* e16   = (_Float16*)alloc((size_t)TC * N * H_DIM * sizeof(_Float16));  // 82 MB
    // recurrent state (double-buffered)
    _Float16* h_a   = (_Float16*)alloc((size_t)N * H_DIM * sizeof(_Float16));
    _Float16* h_b   = (_Float16*)alloc((size_t)N * H_DIM * sizeof(_Float16));

    const int TB = 256;
    hipLaunchKernelGGL(init_deg_kernel, dim3((N + TB - 1) / TB), dim3(TB), 0, stream, deg, indeg, N);
    hipLaunchKernelGGL(accum_deg_kernel, dim3((E + TB - 1) / TB), dim3(TB), 0, stream, src, dst, ew, deg, indeg, E);
    hipLaunchKernelGGL(dinv_kernel, dim3((N + TB - 1) / TB), dim3(TB), 0, stream, deg, selfnorm, N);
    hipLaunchKernelGGL(edge_norm_kernel, dim3((E + TB - 1) / TB), dim3(TB), 0, stream, src, dst, ew, deg, norm, E);
    hipLaunchKernelGGL(scan_kernel, dim3(1), dim3(1024), 0, stream, indeg, offs, cursor, N);
    hipLaunchKernelGGL(csr_fill_kernel, dim3((E + TB - 1) / TB), dim3(TB), 0, stream, src, dst, norm, cursor, csr_src, csr_norm, E);

    // weight packs (fp16) + permuted biases
    {
        int tot = (F_IN / 8) * H_DIM;
        hipLaunchKernelGGL(pack_b16_kernel, dim3((tot + TB - 1) / TB), dim3(TB), 0, stream, W1, W1p, F_IN, H_DIM, 0);
        tot = (H_DIM / 8) * H_DIM;
        hipLaunchKernelGGL(pack_b16_kernel, dim3((tot + TB - 1) / TB), dim3(TB), 0, stream, W2, W2p, H_DIM, H_DIM, 0);
        tot = (H_DIM / 8) * H3;
        hipLaunchKernelGGL(pack_b16_kernel, dim3((tot + TB - 1) / TB), dim3(TB), 0, stream, Wih, Wihp, H_DIM, H3, 2);
        hipLaunchKernelGGL(pack_b16_kernel, dim3((tot + TB - 1) / TB), dim3(TB), 0, stream, Whh, Whhp, H_DIM, H3, 2);
        hipLaunchKernelGGL(perm_bias_kernel, dim3((H3 + TB - 1) / TB), dim3(TB), 0, stream, bih, pbih);
        hipLaunchKernelGGL(perm_bias_kernel, dim3((H3 + TB - 1) / TB), dim3(TB), 0, stream, bhh, pbhh);
    }

    hipMemsetAsync(h_a, 0, (size_t)N * H_DIM * sizeof(_Float16), stream);

    const int MC = TC * N;                   // 160000 (= 1250 * 128 exactly)
    dim3 gb(256);
    dim3 g_conv1(MC / 128, H_DIM / 128);     // (1250, 2)
    dim3 g_c2ln(MC / 128);                   // (1250)
    dim3 g_gru(8 * GRU_BM_GRPS);             // 1280, XCD-swizzled
    dim3 g_agg(N / 4, TC);                   // (5000, 8)

    _Float16* h_cur = h_a;
    _Float16* h_nxt = h_b;

    for (int chunk = 0; chunk < NCHUNK; ++chunk) {
        const float* xc = x + (size_t)chunk * TC * N * F_IN;
        // x -> fp16 (whole chunk)
        int n4 = TC * N * F_IN / 4;
        hipLaunchKernelGGL(tofp16_kernel, dim3((n4 + TB - 1) / TB), dim3(TB), 0, stream, xc, xs16, n4);
        // agg1: a1 = A @ x  (fp16 gather, exact commute)
        hipLaunchKernelGGL(agg1_kernel, g_agg, dim3(256), 0, stream,
                           xs16, offs, csr_src, csr_norm, selfnorm, a1_16, N);
        // conv1: h1 = leaky(a1 @ W1 + b1) -> fp16
        hipLaunchKernelGGL(conv1_kernel, g_conv1, gb, 0, stream,
                           a1_16, W1p, b1, h1_16, MC, H_DIM, F_IN);
        // agg2: a2 = A @ h1
        hipLaunchKernelGGL(agg2_kernel, g_agg, dim3(256), 0, stream,
                           h1_16, offs, csr_src, csr_norm, selfnorm, a2_16, N);
        // conv2 + LN fused -> e16
        hipLaunchKernelGGL(conv2ln_kernel, g_c2ln, gb, 0, stream,
                           a2_16, W2p, b2, lnw, lnb, e16, MC);
        // sequential GRU: fused gi+gh GEMMs + pointwise, double-buffered h
        for (int tc = 0; tc < TC; ++tc) {
            hipLaunchKernelGGL(gru_step_kernel, g_gru, gb, 0, stream,
                               h_cur, e16 + (size_t)tc * N * H_DIM, Whhp, Wihp,
                               pbhh, pbih, h_nxt, N);
            _Float16* tmp = h_cur; h_cur = h_nxt; h_nxt = tmp;
        }
    }

    hipLaunchKernelGGL(fc_kernel, dim3((N + 3) / 4), dim3(256), 0, stream, h_cur, Wfc, bfc, (float*)d_out, N);
}

// Round 14
// 2107.138 us; speedup vs baseline: 1.3814x; 1.0064x over previous
//
#include <hip/hip_runtime.h>
#include <math.h>

// Problem constants (fixed by reference)
#define T_STEPS 24
#define N_NODES 20000
#define F_IN 64
#define H_DIM 256
#define H3 (3 * H_DIM)
#define TC 12                   // timestep chunk for the encoder
#define NCHUNK (T_STEPS / TC)   // 2
#define GRU_BM_GRPS 160         // padded row-groups (157 real) ; 160 % 8 == 0

using f16x8 = __attribute__((ext_vector_type(8))) _Float16;
using f16x4 = __attribute__((ext_vector_type(4))) _Float16;
using f16x2 = __attribute__((ext_vector_type(2))) _Float16;
using f32x4 = __attribute__((ext_vector_type(4))) float;

__device__ __forceinline__ void gload_lds16(const void* g, void* l) {
    __builtin_amdgcn_global_load_lds(
        (const __attribute__((address_space(1))) void*)(uintptr_t)g,
        (__attribute__((address_space(3))) void*)l, 16, 0, 0);
}

__device__ __forceinline__ float sigmoidf_(float x) { return 1.0f / (1.0f + expf(-x)); }

// ---------------------------------------------------------------------------
// Norm / CSR build kernels
// ---------------------------------------------------------------------------
__global__ void init_deg_kernel(float* deg, int* indeg, int n) {
    int i = blockIdx.x * blockDim.x + threadIdx.x;
    if (i < n) { deg[i] = 1.0f; indeg[i] = 0; }
}

__global__ void accum_deg_kernel(const int* __restrict__ src, const int* __restrict__ dst,
                                 const float* __restrict__ ew, float* deg, int* indeg, int E) {
    int e = blockIdx.x * blockDim.x + threadIdx.x;
    if (e < E) {
        atomicAdd(&deg[dst[e]], ew[e]);
        atomicAdd(&indeg[dst[e]], 1);
    }
}

__global__ void dinv_kernel(float* deg, float* selfnorm, int n) {
    int i = blockIdx.x * blockDim.x + threadIdx.x;
    if (i < n) {
        float d = deg[i];
        float di = (d > 0.0f) ? rsqrtf(d) : 0.0f;
        deg[i] = di;
        selfnorm[i] = di * di;
    }
}

__global__ void edge_norm_kernel(const int* __restrict__ src, const int* __restrict__ dst,
                                 const float* __restrict__ ew, const float* __restrict__ dinv,
                                 float* norm, int E) {
    int e = blockIdx.x * blockDim.x + threadIdx.x;
    if (e < E) norm[e] = dinv[src[e]] * ew[e] * dinv[dst[e]];
}

__global__ void scan_kernel(const int* __restrict__ indeg, int* offs, int* cursor, int N) {
    __shared__ int part[1024];
    int t = threadIdx.x;
    const int CH = (N + 1023) / 1024;
    int s = 0;
    for (int i = 0; i < CH; i++) {
        int idx = t * CH + i;
        if (idx < N) s += indeg[idx];
    }
    part[t] = s;
    __syncthreads();
    for (int off = 1; off < 1024; off <<= 1) {
        int v = (t >= off) ? part[t - off] : 0;
        __syncthreads();
        part[t] += v;
        __syncthreads();
    }
    int base = (t == 0) ? 0 : part[t - 1];
    for (int i = 0; i < CH; i++) {
        int idx = t * CH + i;
        if (idx < N) {
            offs[idx] = base;
            cursor[idx] = base;
            base += indeg[idx];
        }
    }
    if (t == 0) offs[N] = part[1023];
}

__global__ void csr_fill_kernel(const int* __restrict__ src, const int* __restrict__ dst,
                                const float* __restrict__ norm, int* cursor,
                                int* csr_src, float* csr_norm, int E) {
    int e = blockIdx.x * blockDim.x + threadIdx.x;
    if (e < E) {
        int d = dst[e];
        int pos = atomicAdd(&cursor[d], 1);
        csr_src[pos] = src[e];
        csr_norm[pos] = norm[e];
    }
}

// ---------------------------------------------------------------------------
// Weight pack (fp16): P[kk][c][j], j=0..7, kk=k/8.
// trans=0: B = W [K,N] row-major.
// trans=2: B = W^T with gate-block-interleaved columns:
//          c -> a=c/48, w=c%48, g=w/16, b=w&15, orig row = g*256 + a*16 + b.
// ---------------------------------------------------------------------------
__global__ void pack_b16_kernel(const float* __restrict__ W, _Float16* __restrict__ P,
                                int K, int Nn, int trans) {
    int idx = blockIdx.x * blockDim.x + threadIdx.x;
    int total = (K >> 3) * Nn;
    if (idx >= total) return;
    int kk = idx / Nn, c = idx - kk * Nn;
    int n = c;
    if (trans == 2) {
        int a = c / 48, w = c % 48;
        int g = w >> 4, b = w & 15;
        n = g * 256 + a * 16 + b;
    }
    size_t o = (size_t)idx * 8;
    for (int j = 0; j < 8; ++j) {
        float v = (trans != 0) ? W[(size_t)n * K + kk * 8 + j] : W[(size_t)(kk * 8 + j) * Nn + n];
        P[o + j] = (_Float16)v;
    }
}

// Permute a [768] bias into gate-block-interleaved order.
__global__ void perm_bias_kernel(const float* __restrict__ b, float* __restrict__ pb) {
    int c = blockIdx.x * blockDim.x + threadIdx.x;
    if (c < H3) {
        int a = c / 48, w = c % 48;
        int g = w >> 4, bb = w & 15;
        pb[c] = b[g * 256 + a * 16 + bb];
    }
}

// fp32 -> fp16 (vectorized x4)
__global__ void tofp16_kernel(const float* __restrict__ in, _Float16* __restrict__ out, int n4) {
    int i = blockIdx.x * blockDim.x + threadIdx.x;
    if (i < n4) {
        float4 v = ((const float4*)in)[i];
        f16x4 o = { (_Float16)v.x, (_Float16)v.y, (_Float16)v.z, (_Float16)v.w };
        ((f16x4*)out)[i] = o;
    }
}

// ---------------------------------------------------------------------------
// agg1 (chunked over TC): fp16 gather. One wave per node, 8-way edge-parallel
// lanes (8 lanes x f16x8 = 128B row), 2-deep unroll (16 edges in flight).
// ---------------------------------------------------------------------------
__global__ void agg1_kernel(const _Float16* __restrict__ xs, const int* __restrict__ offs,
                            const int* __restrict__ csr_src, const float* __restrict__ csr_norm,
                            const float* __restrict__ selfnorm,
                            _Float16* __restrict__ out, int N) {
    int t = blockIdx.y;
    int n = blockIdx.x * 4 + (threadIdx.x >> 6);
    int lane = threadIdx.x & 63;
    int fg = lane & 7, ep = lane >> 3;     // 8 feature-lanes x 8 edge-groups
    const _Float16* xsl = xs + (size_t)t * N * F_IN;
    float acc[8] = {};
    int e0 = offs[n], e1 = offs[n + 1];
    int e = e0 + ep;
    for (; e + 8 < e1; e += 16) {
        int sA = csr_src[e], sB = csr_src[e + 8];
        float wA = csr_norm[e], wB = csr_norm[e + 8];
        f16x8 vA = *(const f16x8*)&xsl[(size_t)sA * F_IN + fg * 8];
        f16x8 vB = *(const f16x8*)&xsl[(size_t)sB * F_IN + fg * 8];
#pragma unroll
        for (int c = 0; c < 8; ++c) acc[c] = fmaf(wA, (float)vA[c], acc[c]);
#pragma unroll
        for (int c = 0; c < 8; ++c) acc[c] = fmaf(wB, (float)vB[c], acc[c]);
    }
    if (e < e1) {
        int s = csr_src[e];
        float w = csr_norm[e];
        f16x8 v = *(const f16x8*)&xsl[(size_t)s * F_IN + fg * 8];
#pragma unroll
        for (int c = 0; c < 8; ++c) acc[c] = fmaf(w, (float)v[c], acc[c]);
    }
#pragma unroll
    for (int c = 0; c < 8; ++c) {
        acc[c] += __shfl_xor(acc[c], 8, 64);
        acc[c] += __shfl_xor(acc[c], 16, 64);
        acc[c] += __shfl_xor(acc[c], 32, 64);
    }
    f16x8 own = *(const f16x8*)&xsl[(size_t)n * F_IN + fg * 8];
    float sn = selfnorm[n];
#pragma unroll
    for (int c = 0; c < 8; ++c) acc[c] = fmaf(sn, (float)own[c], acc[c]);
    if (ep == 0) {
        f16x8 o;
#pragma unroll
        for (int c = 0; c < 8; ++c) o[c] = (_Float16)acc[c];
        *(f16x8*)&out[((size_t)t * N + n) * F_IN + fg * 8] = o;
    }
}

// ---------------------------------------------------------------------------
// agg2 (chunked over TC): one wave per node, HALF-WAVE per edge
// (32 lanes x f16x8 = 512B row). 4 edges per half per iter (8 rows in
// flight/wave). Cross-half combine via one shfl_xor(32).
// ---------------------------------------------------------------------------
__global__ void agg2_kernel(const _Float16* __restrict__ hs, const int* __restrict__ offs,
                            const int* __restrict__ csr_src, const float* __restrict__ csr_norm,
                            const float* __restrict__ selfnorm,
                            _Float16* __restrict__ out, int N) {
    int t = blockIdx.y;
    int n = blockIdx.x * 4 + (threadIdx.x >> 6);
    int lane = threadIdx.x & 63;
    int half = lane >> 5, fl = lane & 31;   // 32 feature-lanes x 2 edge-halves
    const _Float16* hsl = hs + (size_t)t * N * H_DIM;
    float acc[8] = {};
    int e0 = offs[n], e1 = offs[n + 1];
    int e = e0;
    // main: 8 edges/iter, half h takes contiguous run [e+4h, e+4h+4)
    for (; e + 8 <= e1; e += 8) {
        int eb = e + half * 4;
        int s0 = csr_src[eb], s1 = csr_src[eb + 1], s2 = csr_src[eb + 2], s3 = csr_src[eb + 3];
        float w0 = csr_norm[eb], w1 = csr_norm[eb + 1], w2 = csr_norm[eb + 2], w3 = csr_norm[eb + 3];
        f16x8 v0 = *(const f16x8*)&hsl[(size_t)s0 * H_DIM + fl * 8];
        f16x8 v1 = *(const f16x8*)&hsl[(size_t)s1 * H_DIM + fl * 8];
        f16x8 v2 = *(const f16x8*)&hsl[(size_t)s2 * H_DIM + fl * 8];
        f16x8 v3 = *(const f16x8*)&hsl[(size_t)s3 * H_DIM + fl * 8];
#pragma unroll
        for (int c = 0; c < 8; ++c) acc[c] = fmaf(w0, (float)v0[c], acc[c]);
#pragma unroll
        for (int c = 0; c < 8; ++c) acc[c] = fmaf(w1, (float)v1[c], acc[c]);
#pragma unroll
        for (int c = 0; c < 8; ++c) acc[c] = fmaf(w2, (float)v2[c], acc[c]);
#pragma unroll
        for (int c = 0; c < 8; ++c) acc[c] = fmaf(w3, (float)v3[c], acc[c]);
    }
    // pairs: one edge per half
    for (; e + 2 <= e1; e += 2) {
        int eb = e + half;
        int s = csr_src[eb];
        float w = csr_norm[eb];
        f16x8 v = *(const f16x8*)&hsl[(size_t)s * H_DIM + fl * 8];
#pragma unroll
        for (int c = 0; c < 8; ++c) acc[c] = fmaf(w, (float)v[c], acc[c]);
    }
    // last odd edge (half 0 only)
    if (e < e1 && half == 0) {
        int s = csr_src[e];
        float w = csr_norm[e];
        f16x8 v = *(const f16x8*)&hsl[(size_t)s * H_DIM + fl * 8];
#pragma unroll
        for (int c = 0; c < 8; ++c) acc[c] = fmaf(w, (float)v[c], acc[c]);
    }
#pragma unroll
    for (int c = 0; c < 8; ++c) acc[c] += __shfl_xor(acc[c], 32, 64);
    f16x8 own = *(const f16x8*)&hsl[(size_t)n * H_DIM + fl * 8];
    float sn = selfnorm[n];
#pragma unroll
    for (int c = 0; c < 8; ++c) acc[c] = fmaf(sn, (float)own[c], acc[c]);
    if (half == 0) {
        f16x8 o;
#pragma unroll
        for (int c = 0; c < 8; ++c) o[c] = (_Float16)acc[c];
        *(f16x8*)&out[((size_t)t * N + n) * H_DIM + fl * 8] = o;
    }
}

// ---------------------------------------------------------------------------
// conv1: fp16 MFMA GEMM, 128x128 tile, BK=32, bias + leaky -> fp16.
// SWAPPED operands: mfma(b, a, acc) => lane(kq,r) reg q holds
// C[row = wm+i*16+r][col = wn+j*16+kq*4+q] -> f16x4 stores.
// ---------------------------------------------------------------------------
__global__ __launch_bounds__(256, 4)
void conv1_kernel(const _Float16* __restrict__ A, const _Float16* __restrict__ Bp,
                  const float* __restrict__ bias, _Float16* __restrict__ C16,
                  int M, int Nn, int K) {
    __shared__ _Float16 As[4][128][8];
    __shared__ _Float16 Bs[4][128][8];

    const int tid = threadIdx.x;
    const int wave = tid >> 6, lane = tid & 63;
    const int bm = blockIdx.x * 128, bn = blockIdx.y * 128;
    const int wm = (wave >> 1) * 64, wn = (wave & 1) * 64;
    const int kq = lane >> 4, r = lane & 15;

    f32x4 acc[4][4];
#pragma unroll
    for (int i = 0; i < 4; ++i)
#pragma unroll
        for (int j = 0; j < 4; ++j) acc[i][j] = (f32x4){0.f, 0.f, 0.f, 0.f};

    for (int k0 = 0; k0 < K; k0 += 32) {
        __syncthreads();
        const int kb = k0 >> 3;
#pragma unroll
        for (int it = 0; it < 2; ++it) {
            int c = it * 256 + tid;
            int kk = c >> 7, idx = c & 127;
            int row = bm + idx;
            if (row >= M) row = M - 1;
            size_t aoff = (size_t)row * K + k0 + kk * 8;
            size_t boff = ((size_t)(kb + kk) * Nn + bn + idx) * 8;
            gload_lds16(A + aoff, &As[0][0][0] + (size_t)c * 8);
            gload_lds16(Bp + boff, &Bs[0][0][0] + (size_t)c * 8);
        }
        __syncthreads();

        f16x8 a[4], b[4];
#pragma unroll
        for (int f = 0; f < 4; ++f) {
            a[f] = *(const f16x8*)&As[kq][wm + f * 16 + r][0];
            b[f] = *(const f16x8*)&Bs[kq][wn + f * 16 + r][0];
        }
#pragma unroll
        for (int i = 0; i < 4; ++i)
#pragma unroll
            for (int j = 0; j < 4; ++j)
                acc[i][j] = __builtin_amdgcn_mfma_f32_16x16x32_f16(b[j], a[i], acc[i][j], 0, 0, 0);
    }

#pragma unroll
    for (int j = 0; j < 4; ++j) {
        int colb = bn + wn + j * 16 + kq * 4;
        float4 bv = *(const float4*)&bias[colb];
#pragma unroll
        for (int i = 0; i < 4; ++i) {
            int row = bm + wm + i * 16 + r;   // grid covers M exactly (M % 128 == 0)
            f16x4 o;
#pragma unroll
            for (int q = 0; q < 4; ++q) {
                float v = acc[i][j][q] + ((const float*)&bv)[q];
                v = (v >= 0.0f) ? v : 0.01f * v;
                o[q] = (_Float16)v;
            }
            *(f16x4*)&C16[(size_t)row * Nn + colb] = o;
        }
    }
}

// ---------------------------------------------------------------------------
// conv2 + LayerNorm fused (SWAPPED operands): C = A @ W2 + b2; LN per row.
// BM=128, BN=256, 4 waves 2x2 (wave 64x128, acc 4x8). Lane(kq,r) reg q holds
// C[row = wm+i*16+r][col = wn+j*16+kq*4+q]; row-sum = lane 32-sum + kq shfls.
// ---------------------------------------------------------------------------
__global__ __launch_bounds__(256, 2)
void conv2ln_kernel(const _Float16* __restrict__ A, const _Float16* __restrict__ Bp,
                    const float* __restrict__ b2, const float* __restrict__ lnw,
                    const float* __restrict__ lnb, _Float16* __restrict__ out, int M) {
    __shared__ _Float16 As[4][128][8];   // 8 KB
    __shared__ _Float16 Bs[4][256][8];   // 16 KB
    __shared__ float lnP[128][2][2];     // 2 KB

    const int tid = threadIdx.x;
    const int wave = tid >> 6, lane = tid & 63;
    const int bm = blockIdx.x * 128;
    const int wm = (wave >> 1) * 64, wn = (wave & 1) * 128;
    const int cw = wave & 1;
    const int kq = lane >> 4, r = lane & 15;

    f32x4 acc[4][8];
#pragma unroll
    for (int i = 0; i < 4; ++i)
#pragma unroll
        for (int j = 0; j < 8; ++j) acc[i][j] = (f32x4){0.f, 0.f, 0.f, 0.f};

    for (int k0 = 0; k0 < H_DIM; k0 += 32) {
        __syncthreads();
        const int kb = k0 >> 3;
#pragma unroll
        for (int it = 0; it < 2; ++it) {
            int c = it * 256 + tid;
            int kk = c >> 7, idx = c & 127;
            int row = bm + idx;
            if (row >= M) row = M - 1;
            gload_lds16(A + (size_t)row * H_DIM + k0 + kk * 8, &As[0][0][0] + (size_t)c * 8);
        }
#pragma unroll
        for (int it = 0; it < 4; ++it) {
            int c = it * 256 + tid;
            int kk = c >> 8, col = c & 255;
            gload_lds16(Bp + ((size_t)(kb + kk) * H_DIM + col) * 8, &Bs[0][0][0] + (size_t)c * 8);
        }
        __syncthreads();

        f16x8 a[4], b[8];
#pragma unroll
        for (int f = 0; f < 4; ++f) a[f] = *(const f16x8*)&As[kq][wm + f * 16 + r][0];
#pragma unroll
        for (int f = 0; f < 8; ++f) b[f] = *(const f16x8*)&Bs[kq][wn + f * 16 + r][0];
#pragma unroll
        for (int i = 0; i < 4; ++i)
#pragma unroll
            for (int j = 0; j < 8; ++j)
                acc[i][j] = __builtin_amdgcn_mfma_f32_16x16x32_f16(b[j], a[i], acc[i][j], 0, 0, 0);
    }

    // bias add + per-row partial sums: lane's 32 values all belong to row wm+i*16+r
#pragma unroll
    for (int i = 0; i < 4; ++i) {
        float s = 0.f, s2 = 0.f;
#pragma unroll
        for (int j = 0; j < 8; ++j) {
            float4 bv = *(const float4*)&b2[wn + j * 16 + kq * 4];
#pragma unroll
            for (int q = 0; q < 4; ++q) {
                float v = acc[i][j][q] + ((const float*)&bv)[q];
                acc[i][j][q] = v;
                s += v;
                s2 += v * v;
            }
        }
        // combine the 4 kq lanes sharing this row
        s += __shfl_xor(s, 16, 64);  s2 += __shfl_xor(s2, 16, 64);
        s += __shfl_xor(s, 32, 64);  s2 += __shfl_xor(s2, 32, 64);
        int lrow = wm + i * 16 + r;
        if (kq == 0) { lnP[lrow][cw][0] = s; lnP[lrow][cw][1] = s2; }
    }
    __syncthreads();

#pragma unroll
    for (int i = 0; i < 4; ++i) {
        int lrow = wm + i * 16 + r;
        int row = bm + lrow;   // grid covers M exactly
        float S = lnP[lrow][0][0] + lnP[lrow][1][0];
        float S2 = lnP[lrow][0][1] + lnP[lrow][1][1];
        float mu = S * (1.0f / H_DIM);
        float var = S2 * (1.0f / H_DIM) - mu * mu;
        float rstd = rsqrtf(var + 1e-5f);
#pragma unroll
        for (int j = 0; j < 8; ++j) {
            int colb = wn + j * 16 + kq * 4;
            float4 wv = *(const float4*)&lnw[colb];
            float4 bvv = *(const float4*)&lnb[colb];
            f16x4 o;
#pragma unroll
            for (int q = 0; q < 4; ++q)
                o[q] = (_Float16)((acc[i][j][q] - mu) * rstd * ((const float*)&wv)[q] + ((const float*)&bvv)[q]);
            *(f16x4*)&out[(size_t)row * H_DIM + colb] = o;
        }
    }
}

// ---------------------------------------------------------------------------
// Fused GRU step (SWAPPED operands): gh = h@Whh^T, gi = e@Wih^T
// (gate-block-interleaved cols), r/z accs shared. BM=128, BN=96, 4 waves 2x2.
// Lane(kq,r) reg q holds gate value for feature agrp*16 + kq*4 + q of
// row wm+i*16+r -> f16x4 h-load/store. XCD-swizzled 1-D grid.
// ---------------------------------------------------------------------------
__global__ __launch_bounds__(256, 3)
void gru_step_kernel(const _Float16* __restrict__ hprev, const _Float16* __restrict__ e,
                     const _Float16* __restrict__ Bhh, const _Float16* __restrict__ Bih,
                     const float* __restrict__ pbhh, const float* __restrict__ pbih,
                     _Float16* __restrict__ hnew, int M) {
    const int bid = blockIdx.x;
    const int bn_grp = bid / GRU_BM_GRPS;        // 0..7
    const int bm_grp = bid - bn_grp * GRU_BM_GRPS;
    if (bm_grp * 128 >= M) return;               // padding block
    const int bm = bm_grp * 128, bn = bn_grp * 96;

    __shared__ _Float16 Ah[4][128][8];   // 8 KB
    __shared__ _Float16 Ae[4][128][8];   // 8 KB
    __shared__ _Float16 Bsh[4][96][8];   // 6 KB
    __shared__ _Float16 Bsi[4][96][8];   // 6 KB

    const int tid = threadIdx.x;
    const int wave = tid >> 6, lane = tid & 63;
    const int wm = (wave >> 1) * 64, wn = (wave & 1) * 48;
    const int kq = lane >> 4, r = lane & 15;

    f32x4 arz[4][2], ahn[4], ainn[4];
#pragma unroll
    for (int i = 0; i < 4; ++i) {
        arz[i][0] = (f32x4){0.f, 0.f, 0.f, 0.f};
        arz[i][1] = (f32x4){0.f, 0.f, 0.f, 0.f};
        ahn[i] = (f32x4){0.f, 0.f, 0.f, 0.f};
        ainn[i] = (f32x4){0.f, 0.f, 0.f, 0.f};
    }

    for (int k0 = 0; k0 < H_DIM; k0 += 32) {
        __syncthreads();
        const int kb = k0 >> 3;
#pragma unroll
        for (int it = 0; it < 2; ++it) {
            int c = it * 256 + tid;
            int kk = c >> 7, idx = c & 127;
            int row = bm + idx;
            if (row >= M) row = M - 1;
            size_t ao = (size_t)row * H_DIM + k0 + kk * 8;
            gload_lds16(hprev + ao, &Ah[0][0][0] + (size_t)c * 8);
            gload_lds16(e + ao, &Ae[0][0][0] + (size_t)c * 8);
        }
        {
            int c = tid;
            int kk = c / 96, col = c - kk * 96;
            size_t bo = ((size_t)(kb + kk) * H3 + bn + col) * 8;
            gload_lds16(Bhh + bo, &Bsh[0][0][0] + (size_t)c * 8);
            gload_lds16(Bih + bo, &Bsi[0][0][0] + (size_t)c * 8);
            if (tid < 128) {
                int c2 = 256 + tid;
                int kk2 = c2 / 96, col2 = c2 - kk2 * 96;
                size_t bo2 = ((size_t)(kb + kk2) * H3 + bn + col2) * 8;
                gload_lds16(Bhh + bo2, &Bsh[0][0][0] + (size_t)c2 * 8);
                gload_lds16(Bih + bo2, &Bsi[0][0][0] + (size_t)c2 * 8);
            }
        }
        __syncthreads();

        f16x8 ah[4], ae[4], bh[3], bi[3];
#pragma unroll
        for (int f = 0; f < 4; ++f) {
            ah[f] = *(const f16x8*)&Ah[kq][wm + f * 16 + r][0];
            ae[f] = *(const f16x8*)&Ae[kq][wm + f * 16 + r][0];
        }
#pragma unroll
        for (int f = 0; f < 3; ++f) {
            bh[f] = *(const f16x8*)&Bsh[kq][wn + f * 16 + r][0];
            bi[f] = *(const f16x8*)&Bsi[kq][wn + f * 16 + r][0];
        }
#pragma unroll
        for (int i = 0; i < 4; ++i) {
            arz[i][0] = __builtin_amdgcn_mfma_f32_16x16x32_f16(bh[0], ah[i], arz[i][0], 0, 0, 0);
            arz[i][0] = __builtin_amdgcn_mfma_f32_16x16x32_f16(bi[0], ae[i], arz[i][0], 0, 0, 0);
            arz[i][1] = __builtin_amdgcn_mfma_f32_16x16x32_f16(bh[1], ah[i], arz[i][1], 0, 0, 0);
            arz[i][1] = __builtin_amdgcn_mfma_f32_16x16x32_f16(bi[1], ae[i], arz[i][1], 0, 0, 0);
            ahn[i] = __builtin_amdgcn_mfma_f32_16x16x32_f16(bh[2], ah[i], ahn[i], 0, 0, 0);
            ainn[i] = __builtin_amdgcn_mfma_f32_16x16x32_f16(bi[2], ae[i], ainn[i], 0, 0, 0);
        }
    }

    // Epilogue: lane holds gates for features fb..fb+3 of rows wm+i*16+r.
    const int colbase = bn + wn;           // multiple of 48
    const int agrp = colbase / 48;         // 0..15
    const int fb = agrp * 16 + kq * 4;     // feature base (4 consecutive)
    float b_r[4], b_z[4], b_hn[4], b_in[4];
#pragma unroll
    for (int q = 0; q < 4; ++q) {
        int cq = colbase + kq * 4 + q;
        b_r[q]  = pbhh[cq] + pbih[cq];
        b_z[q]  = pbhh[cq + 16] + pbih[cq + 16];
        b_hn[q] = pbhh[cq + 32];
        b_in[q] = pbih[cq + 32];
    }
#pragma unroll
    for (int i = 0; i < 4; ++i) {
        int row = bm + wm + i * 16 + r;
        if (row < M) {
            f16x4 hp = *(const f16x4*)&hprev[(size_t)row * H_DIM + fb];
            f16x4 o;
#pragma unroll
            for (int q = 0; q < 4; ++q) {
                float rg = sigmoidf_(arz[i][0][q] + b_r[q]);
                float zg = sigmoidf_(arz[i][1][q] + b_z[q]);
                float nn = tanhf(ainn[i][q] + b_in[q] + rg * (ahn[i][q] + b_hn[q]));
                o[q] = (_Float16)((1.0f - zg) * nn + zg * (float)hp[q]);
            }
            *(f16x4*)&hnew[(size_t)row * H_DIM + fb] = o;
        }
    }
}

// ---------------------------------------------------------------------------
// fc: out[n] = dot(h16[n,:], Wfc[0,:]) + bfc
// ---------------------------------------------------------------------------
__global__ void fc_kernel(const _Float16* __restrict__ h, const float* __restrict__ Wfc,
                          const float* __restrict__ bfc, float* __restrict__ out, int N) {
    int n = blockIdx.x * 4 + (threadIdx.x >> 6);
    int lane = threadIdx.x & 63;
    if (n >= N) return;
    f16x4 hv = *(const f16x4*)&h[(size_t)n * H_DIM + lane * 4];
    float4 wv = *(const float4*)&Wfc[lane * 4];
    float acc = (float)hv[0] * wv.x + (float)hv[1] * wv.y + (float)hv[2] * wv.z + (float)hv[3] * wv.w;
#pragma unroll
    for (int o = 32; o > 0; o >>= 1) acc += __shfl_down(acc, o, 64);
    if (lane == 0) out[n] = acc + bfc[0];
}

// ---------------------------------------------------------------------------
// Launch
// ---------------------------------------------------------------------------
extern "C" void kernel_launch(void* const* d_in, const int* in_sizes, int n_in,
                              void* d_out, int out_size, void* d_ws, size_t ws_size,
                              hipStream_t stream) {
    const float* x   = (const float*)d_in[0];
    const int* eidx  = (const int*)d_in[1];
    const float* ew  = (const float*)d_in[2];
    const float* W1  = (const float*)d_in[3];
    const float* b1  = (const float*)d_in[4];
    const float* W2  = (const float*)d_in[5];
    const float* b2  = (const float*)d_in[6];
    const float* lnw = (const float*)d_in[7];
    const float* lnb = (const float*)d_in[8];
    const float* Wih = (const float*)d_in[9];
    const float* Whh = (const float*)d_in[10];
    const float* bih = (const float*)d_in[11];
    const float* bhh = (const float*)d_in[12];
    const float* Wfc = (const float*)d_in[13];
    const float* bfc = (const float*)d_in[14];

    const int E = in_sizes[2];
    const int N = N_NODES;
    const int* src = eidx;
    const int* dst = eidx + E;

    uintptr_t p = (uintptr_t)d_ws;
    auto alloc = [&](size_t bytes) -> void* {
        p = (p + 255) & ~(uintptr_t)255;
        void* r = (void*)p;
        p += bytes;
        return r;
    };
    // CSR / norm (~4.2 MB)
    float* deg      = (float*)alloc(N * sizeof(float));
    float* selfnorm = (float*)alloc(N * sizeof(float));
    float* norm     = (float*)alloc(E * sizeof(float));
    int* indeg      = (int*)alloc(N * sizeof(int));
    int* offs       = (int*)alloc((N + 1) * sizeof(int));
    int* cursor     = (int*)alloc(N * sizeof(int));
    int* csr_src    = (int*)alloc(E * sizeof(int));
    float* csr_norm = (float*)alloc(E * sizeof(float));
    // packed fp16 weights + permuted biases (~0.9 MB)
    _Float16* W1p   = (_Float16*)alloc((size_t)F_IN * H_DIM * sizeof(_Float16));
    _Float16* W2p   = (_Float16*)alloc((size_t)H_DIM * H_DIM * sizeof(_Float16));
    _Float16* Wihp  = (_Float16*)alloc((size_t)H_DIM * H3 * sizeof(_Float16));
    _Float16* Whhp  = (_Float16*)alloc((size_t)H_DIM * H3 * sizeof(_Float16));
    float* pbih     = (float*)alloc(H3 * sizeof(float));
    float* pbhh     = (float*)alloc(H3 * sizeof(float));
    // chunk activations (TC=12): 30.7+30.7+122.9+122.9+122.9 = 430 MB
    _Float16* xs16  = (_Float16*)alloc((size_t)TC * N * F_IN * sizeof(_Float16));
    _Float16* a1_16 = (_Float16*)alloc((size_t)TC * N * F_IN * sizeof(_Float16));
    _Float16* h1_16 = (_Float16*)alloc((size_t)TC * N * H_DIM * sizeof(_Float16));
    _Float16* a2_16 = (_Float16*)alloc((size_t)TC * N * H_DIM * sizeof(_Float16));
    _Float16* e16   = (_Float16*)alloc((size_t)TC * N * H_DIM * sizeof(_Float16));
    // recurrent state (double-buffered, 20.5 MB)
    _Float16* h_a   = (_Float16*)alloc((size_t)N * H_DIM * sizeof(_Float16));
    _Float16* h_b   = (_Float16*)alloc((size_t)N * H_DIM * sizeof(_Float16));

    const int TB = 256;
    hipLaunchKernelGGL(init_deg_kernel, dim3((N + TB - 1) / TB), dim3(TB), 0, stream, deg, indeg, N);
    hipLaunchKernelGGL(accum_deg_kernel, dim3((E + TB - 1) / TB), dim3(TB), 0, stream, src, dst, ew, deg, indeg, E);
    hipLaunchKernelGGL(dinv_kernel, dim3((N + TB - 1) / TB), dim3(TB), 0, stream, deg, selfnorm, N);
    hipLaunchKernelGGL(edge_norm_kernel, dim3((E + TB - 1) / TB), dim3(TB), 0, stream, src, dst, ew, deg, norm, E);
    hipLaunchKernelGGL(scan_kernel, dim3(1), dim3(1024), 0, stream, indeg, offs, cursor, N);
    hipLaunchKernelGGL(csr_fill_kernel, dim3((E + TB - 1) / TB), dim3(TB), 0, stream, src, dst, norm, cursor, csr_src, csr_norm, E);

    // weight packs (fp16) + permuted biases
    {
        int tot = (F_IN / 8) * H_DIM;
        hipLaunchKernelGGL(pack_b16_kernel, dim3((tot + TB - 1) / TB), dim3(TB), 0, stream, W1, W1p, F_IN, H_DIM, 0);
        tot = (H_DIM / 8) * H_DIM;
        hipLaunchKernelGGL(pack_b16_kernel, dim3((tot + TB - 1) / TB), dim3(TB), 0, stream, W2, W2p, H_DIM, H_DIM, 0);
        tot = (H_DIM / 8) * H3;
        hipLaunchKernelGGL(pack_b16_kernel, dim3((tot + TB - 1) / TB), dim3(TB), 0, stream, Wih, Wihp, H_DIM, H3, 2);
        hipLaunchKernelGGL(pack_b16_kernel, dim3((tot + TB - 1) / TB), dim3(TB), 0, stream, Whh, Whhp, H_DIM, H3, 2);
        hipLaunchKernelGGL(perm_bias_kernel, dim3((H3 + TB - 1) / TB), dim3(TB), 0, stream, bih, pbih);
        hipLaunchKernelGGL(perm_bias_kernel, dim3((H3 + TB - 1) / TB), dim3(TB), 0, stream, bhh, pbhh);
    }

    hipMemsetAsync(h_a, 0, (size_t)N * H_DIM * sizeof(_Float16), stream);

    const int MC = TC * N;                   // 240000 (= 1875 * 128 exactly)
    dim3 gb(256);
    dim3 g_conv1(MC / 128, H_DIM / 128);     // (1875, 2)
    dim3 g_c2ln(MC / 128);                   // (1875)
    dim3 g_gru(8 * GRU_BM_GRPS);             // 1280, XCD-swizzled
    dim3 g_agg(N / 4, TC);                   // (5000, 12)

    _Float16* h_cur = h_a;
    _Float16* h_nxt = h_b;

    for (int chunk = 0; chunk < NCHUNK; ++chunk) {
        const float* xc = x + (size_t)chunk * TC * N * F_IN;
        // x -> fp16 (whole chunk)
        int n4 = TC * N * F_IN / 4;
        hipLaunchKernelGGL(tofp16_kernel, dim3((n4 + TB - 1) / TB), dim3(TB), 0, stream, xc, xs16, n4);
        // agg1: a1 = A @ x  (fp16 gather, exact commute)
        hipLaunchKernelGGL(agg1_kernel, g_agg, dim3(256), 0, stream,
                           xs16, offs, csr_src, csr_norm, selfnorm, a1_16, N);
        // conv1: h1 = leaky(a1 @ W1 + b1) -> fp16
        hipLaunchKernelGGL(conv1_kernel, g_conv1, gb, 0, stream,
                           a1_16, W1p, b1, h1_16, MC, H_DIM, F_IN);
        // agg2: a2 = A @ h1
        hipLaunchKernelGGL(agg2_kernel, g_agg, dim3(256), 0, stream,
                           h1_16, offs, csr_src, csr_norm, selfnorm, a2_16, N);
        // conv2 + LN fused -> e16
        hipLaunchKernelGGL(conv2ln_kernel, g_c2ln, gb, 0, stream,
                           a2_16, W2p, b2, lnw, lnb, e16, MC);
        // sequential GRU: fused gi+gh GEMMs + pointwise, double-buffered h
        for (int tc = 0; tc < TC; ++tc) {
            hipLaunchKernelGGL(gru_step_kernel, g_gru, gb, 0, stream,
                               h_cur, e16 + (size_t)tc * N * H_DIM, Whhp, Wihp,
                               pbhh, pbih, h_nxt, N);
            _Float16* tmp = h_cur; h_cur = h_nxt; h_nxt = tmp;
        }
    }

    hipLaunchKernelGGL(fc_kernel, dim3((N + 3) / 4), dim3(256), 0, stream, h_cur, Wfc, bfc, (float*)d_out, N);
}